// Round 7
// baseline (404.616 us; speedup 1.0000x reference)
//
#include <hip/hip_runtime.h>
#include <hip/hip_fp16.h>
#include <cstdint>
#include <cstddef>
#include <cstring>

// ---------------- bf16 pack/unpack helpers (RNE) ----------------

__device__ inline unsigned pack_bf16x2(float a, float b) {
    unsigned ua = __float_as_uint(a);
    unsigned ub = __float_as_uint(b);
    ua += 0x7fffu + ((ua >> 16) & 1u);
    ub += 0x7fffu + ((ub >> 16) & 1u);
    return (ua >> 16) | (ub & 0xffff0000u);
}
__device__ inline unsigned short bf16_rne(float v) {
    unsigned u = __float_as_uint(v);
    u += 0x7fffu + ((u >> 16) & 1u);
    return (unsigned short)(u >> 16);
}

// ---------------- fp8 (OCP e4m3fn) pack/unpack ----------------

typedef float fv2 __attribute__((ext_vector_type(2)));

template <bool HI>
__device__ inline fv2 fp8_fv2(unsigned u) {
#if __has_builtin(__builtin_amdgcn_cvt_pk_f32_fp8)
    return __builtin_amdgcn_cvt_pk_f32_fp8((int)u, HI);
#else
    unsigned u2 = HI ? (u >> 16) : (u & 0xffffu);
    unsigned w = (u2 & 0xFFu) | ((u2 & 0xFF00u) << 8);
    unsigned hb = ((w & 0x00800080u) << 8) | ((w & 0x007f007fu) << 7);
    __half2 h2;
    memcpy(&h2, &hb, 4);
    float2 f = __half22float2(h2);
    fv2 r;
    r.x = f.x * 256.0f;
    r.y = f.y * 256.0f;
    return r;
#endif
}

// bf16 pair (packed in a uint) -> fv2  (2 bitops, then packed add on use)
__device__ inline fv2 bfpair(unsigned u) {
    union { unsigned q[2]; fv2 f; } t;
    t.q[0] = u << 16;
    t.q[1] = u & 0xffff0000u;
    return t.f;
}

__device__ inline unsigned f32_to_fp8_byte(float v) {
    unsigned short hb = __half_as_ushort(__float2half(v * 0.00390625f));  // v/256
    unsigned t = hb & 0x7fffu;
    t += 0x3fu + ((t >> 7) & 1u);
    return ((hb >> 8) & 0x80u) | (t >> 7);
}

__device__ inline unsigned char f32_to_fp8_b(float v) {
#if __has_builtin(__builtin_amdgcn_cvt_pk_fp8_f32)
    return (unsigned char)(__builtin_amdgcn_cvt_pk_fp8_f32(v, v, 0, false) & 0xff);
#else
    return (unsigned char)f32_to_fp8_byte(v);
#endif
}

typedef int iv4 __attribute__((ext_vector_type(4)));

#define NPART 8
#define KB    32
#define NPP_MAX 12500

// ---------------- CSR build: single fused kernel with grid barriers --------
// R7: the R6 chain (bucket_ballot -> count_part -> indeg_scan -> scan_partials
// -> finalize_bases -> fill2) is fused into ONE 256-block kernel. R2->R6
// showed deleting dispatches+traffic bought far less than predicted; the
// remaining CSR cost is per-kernel ramp/drain tails, serialized 6 deep.
// Grid barriers: 4 single-use device-scope counters + agent fences. 256
// blocks x 256 thr x 51KB LDS <= 1 block/CU on 256 CUs => co-resident by
// construction (stream-serialized, nothing else running).
// All phase data structures are bit-identical to R6's proven kernels:
//  - ballot bucket (zero per-edge atomics; R5 lesson: no global per-edge atomics)
//  - KB=32 partitioned LDS histograms; L2-windowed col fill (R3 lesson)

__device__ inline void grid_bar(int* ctr, int nb) {
    __syncthreads();
    if (threadIdx.x == 0) {
        __threadfence();
        __hip_atomic_fetch_add(ctr, 1, __ATOMIC_RELEASE, __HIP_MEMORY_SCOPE_AGENT);
        while (__hip_atomic_load(ctr, __ATOMIC_ACQUIRE, __HIP_MEMORY_SCOPE_AGENT) < nb)
            __builtin_amdgcn_s_sleep(1);
        __threadfence();
    }
    __syncthreads();
}

__global__ __launch_bounds__(256) void k_mega_csr(const int* __restrict__ src,
                                                  const int* __restrict__ dst,
                                                  int* __restrict__ cursor8,
                                                  unsigned* __restrict__ pairs,
                                                  int* __restrict__ cntarr,
                                                  float* __restrict__ dinv,
                                                  int* __restrict__ row_ptr,
                                                  int* __restrict__ gpart,
                                                  int* __restrict__ bar,
                                                  int* __restrict__ col,
                                                  int E, int n, int npp, int capE,
                                                  int srcb, int nscan) {
    __shared__ int h[NPP_MAX];
    __shared__ int s[256];
    __shared__ int sWcnt[4][NPART], sWoff[4][NPART];
    const int g = blockIdx.x;
    const int nb = gridDim.x;
    const int tid = threadIdx.x;
    const int p = g & (NPART - 1);
    const int b = g >> 3;
    const int wv = tid >> 6;
    const int lane = tid & 63;

    // ===== phase 0: ballot bucket (R6-proven; per-block contiguous range) ===
    int epb = ((E + nb - 1) / nb + 7) & ~7;   // mult of 8 -> iv4-aligned bases
    int e0 = g * epb, e1 = min(E, e0 + epb);
    unsigned long long below = (1ull << lane) - 1ull;
    for (int c0 = e0; c0 < e1; c0 += 2048) {
        int base_e = c0 + tid * 8;
        int nv = min(8, e1 - base_e);
        if (nv < 0) nv = 0;
        int dv[8], sv[8];
        if (nv == 8) {
            *(iv4*)(dv + 0) = *(const iv4*)(dst + base_e + 0);
            *(iv4*)(dv + 4) = *(const iv4*)(dst + base_e + 4);
            *(iv4*)(sv + 0) = *(const iv4*)(src + base_e + 0);
            *(iv4*)(sv + 4) = *(const iv4*)(src + base_e + 4);
        } else {
            for (int k = 0; k < 8; ++k) {
                dv[k] = (k < nv) ? dst[base_e + k] : -1;
                sv[k] = (k < nv) ? src[base_e + k] : 0;
            }
        }
        int wb[NPART];
#pragma unroll
        for (int pp = 0; pp < NPART; ++pp) wb[pp] = 0;
        int pv[8], pos[8];
#pragma unroll
        for (int ss = 0; ss < 8; ++ss) {
            int d = dv[ss];
            int pp2 = (d >= 0) ? (int)((unsigned)d / (unsigned)npp) : NPART;
            pv[ss] = pp2;
            unsigned long long msel = 0;
            int base = 0;
#pragma unroll
            for (int pp = 0; pp < NPART; ++pp) {
                unsigned long long m = __ballot(pp2 == pp);
                if (pp2 == pp) { msel = m; base = wb[pp]; }
                wb[pp] += (int)__popcll(m);   // wave-uniform
            }
            pos[ss] = base + (int)__popcll(msel & below);
        }
        if (lane < NPART) {
            int v = 0;
#pragma unroll
            for (int pp = 0; pp < NPART; ++pp)
                if (lane == pp) v = wb[pp];
            sWcnt[wv][lane] = v;
        }
        __syncthreads();
        if (tid < NPART) {
            int c0w = sWcnt[0][tid], c1w = sWcnt[1][tid];
            int c2w = sWcnt[2][tid], c3w = sWcnt[3][tid];
            int gb = atomicAdd(&cursor8[tid], c0w + c1w + c2w + c3w);
            sWoff[0][tid] = gb;
            sWoff[1][tid] = gb + c0w;
            sWoff[2][tid] = gb + c0w + c1w;
            sWoff[3][tid] = gb + c0w + c1w + c2w;
        }
        __syncthreads();
#pragma unroll
        for (int ss = 0; ss < 8; ++ss) {
            int pp2 = pv[ss];
            if (pp2 < NPART) {
                int off = sWoff[wv][pp2];
                pairs[(size_t)pp2 * capE + off + pos[ss]] =
                    ((unsigned)(dv[ss] - pp2 * npp) << srcb) | (unsigned)sv[ss];
            }
        }
        __syncthreads();
    }
    grid_bar(bar + 0, nb);

    // ===== phase 1: per-(partition, sub-block) LDS histogram ===============
    for (int i = tid; i < npp; i += 256) h[i] = 0;
    __syncthreads();
    int szp = cursor8[p];
    int chunk = (szp + KB - 1) / KB;
    int cs0 = b * chunk, cs1 = min(szp, cs0 + chunk);
    const unsigned* seg = pairs + (size_t)p * capE;
    for (int i = cs0 + tid; i < cs1; i += 256)
        atomicAdd(&h[seg[i] >> srcb], 1);
    __syncthreads();
    {
        size_t outS = (size_t)(p * KB + b) * npp;
        for (int i = tid; i < npp; i += 256) cntarr[outS + i] = h[i];
    }
    grid_bar(bar + 1, nb);

    // ===== phase 2: indeg (sum 32 slices) -> dinv + block-local scan =======
    if (g < nscan) {
        int node0 = g * 1024 + tid * 4;
        int v0 = 0, v1 = 0, v2 = 0, v3 = 0;
        if (((npp & 3) == 0) && (node0 + 3 < n) && (node0 / npp == (node0 + 3) / npp)) {
            int pp = node0 / npp;
            int dl = node0 - pp * npp;
            size_t base = (size_t)pp * KB * npp + dl;
            for (int bb = 0; bb < KB; ++bb) {
                iv4 c = *(const iv4*)(cntarr + base + (size_t)bb * npp);
                v0 += c.x; v1 += c.y; v2 += c.z; v3 += c.w;
            }
        } else {
            for (int r = 0; r < 4; ++r) {
                int node = node0 + r;
                if (node < n) {
                    int pp = node / npp;
                    int dl = node - pp * npp;
                    size_t base = (size_t)pp * KB * npp + dl;
                    int sum = 0;
                    for (int bb = 0; bb < KB; ++bb) sum += cntarr[base + (size_t)bb * npp];
                    if (r == 0) v0 = sum; else if (r == 1) v1 = sum;
                    else if (r == 2) v2 = sum; else v3 = sum;
                }
            }
        }
        if (node0 + 0 < n) dinv[node0 + 0] = rsqrtf((float)v0 + 1.0f);
        if (node0 + 1 < n) dinv[node0 + 1] = rsqrtf((float)v1 + 1.0f);
        if (node0 + 2 < n) dinv[node0 + 2] = rsqrtf((float)v2 + 1.0f);
        if (node0 + 3 < n) dinv[node0 + 3] = rsqrtf((float)v3 + 1.0f);
        int sum = v0 + v1 + v2 + v3;
        s[tid] = sum;
        __syncthreads();
        for (int off = 1; off < 256; off <<= 1) {
            int x = (tid >= off) ? s[tid - off] : 0;
            __syncthreads();
            s[tid] += x;
            __syncthreads();
        }
        int excl = s[tid] - sum;
        if ((node0 + 0) < n) row_ptr[node0 + 0] = excl;
        if ((node0 + 1) < n) row_ptr[node0 + 1] = excl + v0;
        if ((node0 + 2) < n) row_ptr[node0 + 2] = excl + v0 + v1;
        if ((node0 + 3) < n) row_ptr[node0 + 3] = excl + v0 + v1 + v2;
        if (tid == 255) gpart[g] = s[255];
    } else {
        if (tid == 0) gpart[g] = 0;
    }
    grid_bar(bar + 2, nb);

    // ===== phase 3: scan partials (redundant per block) + finalize bases ===
    {
        int v = gpart[tid];
        s[tid] = v;
        __syncthreads();
        for (int off = 1; off < 256; off <<= 1) {
            int x = (tid >= off) ? s[tid - off] : 0;
            __syncthreads();
            s[tid] += x;
            __syncthreads();
        }
        int excl = s[tid] - v;
        __syncthreads();
        s[tid] = excl;
        __syncthreads();
    }
    {
        int ch3 = (n + nb - 1) / nb;
        int i0 = g * ch3, i1 = min(n, i0 + ch3);
        for (int i = i0 + tid; i < i1; i += 256) {
            int rp = row_ptr[i] + s[i >> 10];
            row_ptr[i] = rp;
            int pp = (unsigned)i / (unsigned)npp;
            int dl = i - pp * npp;
            size_t base = (size_t)pp * KB * npp + dl;
            int run = rp;
            for (int bb = 0; bb < KB; ++bb) {
                size_t idx = base + (size_t)bb * npp;
                int c = cntarr[idx];
                cntarr[idx] = run;
                run += c;
            }
        }
        if (g == 0 && tid == 0) row_ptr[n] = E;
    }
    grid_bar(bar + 3, nb);

    // ===== phase 4: L2-windowed fill (cursors in LDS) ======================
    {
        size_t slice = (size_t)(p * KB + b) * npp;
        for (int i = tid; i < npp; i += 256) h[i] = cntarr[slice + i];
        __syncthreads();
        unsigned smask = (1u << srcb) - 1u;
        for (int i = cs0 + tid; i < cs1; i += 256) {
            unsigned u = seg[i];
            int pos = atomicAdd(&h[u >> srcb], 1);
            col[pos] = (int)(u & smask);
        }
    }
}

// ---------------- MFMA GEMMs ----------------
typedef __attribute__((ext_vector_type(8))) short short8;
typedef __attribute__((ext_vector_type(4))) float f32x4;

union FragU {
    short8 s;
    uint4 u4;
    unsigned u[4];
};

__device__ inline void packW_body(const float* __restrict__ W, unsigned* __restrict__ Bp,
                                  int NOUT, int NT) {
    int nf = 4 * NT * 64;
    for (int fid = threadIdx.x; fid < nf; fid += 256) {
        int q = fid / (NT * 64);
        int rem = fid - q * NT * 64;
        int nt = rem >> 6;
        int lane = rem & 63;
        int k0 = q * 32 + (lane >> 4) * 8;
        int ncol = nt * 16 + (lane & 15);
        unsigned u[4];
        for (int h = 0; h < 4; ++h) {
            float a = W[(k0 + 2 * h) * NOUT + ncol];
            float b = W[(k0 + 2 * h + 1) * NOUT + ncol];
            u[h] = pack_bf16x2(a, b);
        }
        uint4 o = {u[0], u[1], u[2], u[3]};
        *(uint4*)(Bp + (size_t)fid * 4) = o;
    }
}

// both weight packs in one dispatch; block 0 also zeroes cursor8 + barriers
__global__ void k_packW2(const float* __restrict__ W1, unsigned* __restrict__ Bp1,
                         const float* __restrict__ W2, unsigned* __restrict__ Bp2,
                         int* __restrict__ cursor8, int* __restrict__ bar) {
    if (blockIdx.x == 0) {
        if (threadIdx.x < 8) cursor8[threadIdx.x] = 0;
        else if (threadIdx.x < 16) bar[threadIdx.x - 8] = 0;
        packW_body(W1, Bp1, 128, 8);
    } else {
        packW_body(W2, Bp2, 64, 4);
    }
}

__global__ __launch_bounds__(256) void k_gemm128_mfma(const float* __restrict__ X,
                                                      const unsigned* __restrict__ Bp,
                                                      const float* __restrict__ dinv,
                                                      unsigned char* __restrict__ H8,
                                                      int n) {
    int w = threadIdx.x >> 6;
    int lane = threadIdx.x & 63;
    int quad = lane >> 4;
    int lrow = lane & 15;
    int row0 = blockIdx.x * 64 + w * 16;
    int rowA = min(row0 + lrow, n - 1);

    f32x4 acc[8];
    for (int nt = 0; nt < 8; ++nt) acc[nt] = (f32x4){0.f, 0.f, 0.f, 0.f};

    for (int q = 0; q < 4; ++q) {
        const float* xp = X + (size_t)rowA * 128 + q * 32 + quad * 8;
        float4 x0 = *(const float4*)xp;
        float4 x1 = *(const float4*)(xp + 4);
        FragU a;
        a.u[0] = pack_bf16x2(x0.x, x0.y);
        a.u[1] = pack_bf16x2(x0.z, x0.w);
        a.u[2] = pack_bf16x2(x1.x, x1.y);
        a.u[3] = pack_bf16x2(x1.z, x1.w);
        for (int nt = 0; nt < 8; ++nt) {
            FragU b;
            b.u4 = *(const uint4*)(Bp + ((size_t)(q * 8 + nt) * 64 + lane) * 4);
            acc[nt] = __builtin_amdgcn_mfma_f32_16x16x32_bf16(a.s, b.s, acc[nt], 0, 0, 0);
        }
    }

    int rbase = row0 + quad * 4;
    float dv[4];
    if (rbase + 3 < n) {
        float4 d4 = *(const float4*)(dinv + rbase);
        dv[0] = d4.x; dv[1] = d4.y; dv[2] = d4.z; dv[3] = d4.w;
    } else {
        for (int r = 0; r < 4; ++r) dv[r] = dinv[min(rbase + r, n - 1)];
    }
    for (int nt = 0; nt < 8; ++nt) {
        for (int r = 0; r < 4; ++r) {
            int row = rbase + r;
            if (row < n)
                H8[(size_t)row * 128 + nt * 16 + lrow] = f32_to_fp8_b(dv[r] * acc[nt][r]);
        }
    }
}

__global__ __launch_bounds__(256) void k_gemm64_mfma(const unsigned* __restrict__ Xb,
                                                     const unsigned* __restrict__ Bp,
                                                     const float* __restrict__ dinv,
                                                     unsigned short* __restrict__ H16,
                                                     int n) {
    int w = threadIdx.x >> 6;
    int lane = threadIdx.x & 63;
    int quad = lane >> 4;
    int lrow = lane & 15;
    int row0 = blockIdx.x * 64 + w * 16;
    int rowA = min(row0 + lrow, n - 1);

    f32x4 acc[4];
    for (int nt = 0; nt < 4; ++nt) acc[nt] = (f32x4){0.f, 0.f, 0.f, 0.f};

    for (int q = 0; q < 4; ++q) {
        FragU a;
        a.u4 = *(const uint4*)(Xb + (size_t)rowA * 64 + q * 16 + quad * 4);
        for (int nt = 0; nt < 4; ++nt) {
            FragU b;
            b.u4 = *(const uint4*)(Bp + ((size_t)(q * 4 + nt) * 64 + lane) * 4);
            acc[nt] = __builtin_amdgcn_mfma_f32_16x16x32_bf16(a.s, b.s, acc[nt], 0, 0, 0);
        }
    }

    int rbase = row0 + quad * 4;
    float dv[4];
    if (rbase + 3 < n) {
        float4 d4 = *(const float4*)(dinv + rbase);
        dv[0] = d4.x; dv[1] = d4.y; dv[2] = d4.z; dv[3] = d4.w;
    } else {
        for (int r = 0; r < 4; ++r) dv[r] = dinv[min(rbase + r, n - 1)];
    }
    for (int nt = 0; nt < 4; ++nt) {
        for (int r = 0; r < 4; ++r) {
            int row = rbase + r;
            if (row < n)
                H16[(size_t)row * 64 + nt * 16 + lrow] = bf16_rne(dv[r] * acc[nt][r]);
        }
    }
}

// ---------------- Pull-mode aggregation: quarter-wave PER NODE ----------------
// R13-proven structure: each 16-lane quarter owns ONE node; lane l owns bytes
// 8l..8l+7 of the node's 128 B feature row. No cross-lane reduce in layer 1;
// col indices are quarter-uniform scalar loads; 8-edge unroll keeps 8 loads
// in flight per lane.

// Layer 1: hs rows = 16 uint2 (128 fp8). Lane owns fp8 cols 8l..8l+7.
__global__ __launch_bounds__(256) void k_agg_relu(const unsigned* __restrict__ hs,
                                                  const float* __restrict__ dinv,
                                                  const int* __restrict__ row_ptr,
                                                  const int* __restrict__ col,
                                                  const float* __restrict__ bias,
                                                  unsigned* __restrict__ out, int n) {
    int node = blockIdx.x * 16 + (threadIdx.x >> 4);
    if (node >= n) return;
    int l = threadIdx.x & 15;
    const uint2* hrow = (const uint2*)hs;
    fv2 a0 = {0.f, 0.f}, a1 = {0.f, 0.f}, a2 = {0.f, 0.f}, a3 = {0.f, 0.f};
    {   // self term
        uint2 u = hrow[(size_t)node * 16 + l];
        a0 += fp8_fv2<false>(u.x); a1 += fp8_fv2<true>(u.x);
        a2 += fp8_fv2<false>(u.y); a3 += fp8_fv2<true>(u.y);
    }
    int k = row_ptr[node], p1 = row_ptr[node + 1];
    for (; k + 8 <= p1; k += 8) {  // 8 edges/quarter, 8 loads in flight/lane
        int cA = col[k + 0], cB = col[k + 1], cC = col[k + 2], cD = col[k + 3];
        int cE = col[k + 4], cF = col[k + 5], cG = col[k + 6], cH = col[k + 7];
        uint2 uA = hrow[(size_t)cA * 16 + l];
        uint2 uB = hrow[(size_t)cB * 16 + l];
        uint2 uC = hrow[(size_t)cC * 16 + l];
        uint2 uD = hrow[(size_t)cD * 16 + l];
        uint2 uE = hrow[(size_t)cE * 16 + l];
        uint2 uF = hrow[(size_t)cF * 16 + l];
        uint2 uG = hrow[(size_t)cG * 16 + l];
        uint2 uH = hrow[(size_t)cH * 16 + l];
        a0 += fp8_fv2<false>(uA.x); a1 += fp8_fv2<true>(uA.x);
        a2 += fp8_fv2<false>(uA.y); a3 += fp8_fv2<true>(uA.y);
        a0 += fp8_fv2<false>(uB.x); a1 += fp8_fv2<true>(uB.x);
        a2 += fp8_fv2<false>(uB.y); a3 += fp8_fv2<true>(uB.y);
        a0 += fp8_fv2<false>(uC.x); a1 += fp8_fv2<true>(uC.x);
        a2 += fp8_fv2<false>(uC.y); a3 += fp8_fv2<true>(uC.y);
        a0 += fp8_fv2<false>(uD.x); a1 += fp8_fv2<true>(uD.x);
        a2 += fp8_fv2<false>(uD.y); a3 += fp8_fv2<true>(uD.y);
        a0 += fp8_fv2<false>(uE.x); a1 += fp8_fv2<true>(uE.x);
        a2 += fp8_fv2<false>(uE.y); a3 += fp8_fv2<true>(uE.y);
        a0 += fp8_fv2<false>(uF.x); a1 += fp8_fv2<true>(uF.x);
        a2 += fp8_fv2<false>(uF.y); a3 += fp8_fv2<true>(uF.y);
        a0 += fp8_fv2<false>(uG.x); a1 += fp8_fv2<true>(uG.x);
        a2 += fp8_fv2<false>(uG.y); a3 += fp8_fv2<true>(uG.y);
        a0 += fp8_fv2<false>(uH.x); a1 += fp8_fv2<true>(uH.x);
        a2 += fp8_fv2<false>(uH.y); a3 += fp8_fv2<true>(uH.y);
    }
    for (; k + 4 <= p1; k += 4) {
        int cA = col[k + 0], cB = col[k + 1], cC = col[k + 2], cD = col[k + 3];
        uint2 uA = hrow[(size_t)cA * 16 + l];
        uint2 uB = hrow[(size_t)cB * 16 + l];
        uint2 uC = hrow[(size_t)cC * 16 + l];
        uint2 uD = hrow[(size_t)cD * 16 + l];
        a0 += fp8_fv2<false>(uA.x); a1 += fp8_fv2<true>(uA.x);
        a2 += fp8_fv2<false>(uA.y); a3 += fp8_fv2<true>(uA.y);
        a0 += fp8_fv2<false>(uB.x); a1 += fp8_fv2<true>(uB.x);
        a2 += fp8_fv2<false>(uB.y); a3 += fp8_fv2<true>(uB.y);
        a0 += fp8_fv2<false>(uC.x); a1 += fp8_fv2<true>(uC.x);
        a2 += fp8_fv2<false>(uC.y); a3 += fp8_fv2<true>(uC.y);
        a0 += fp8_fv2<false>(uD.x); a1 += fp8_fv2<true>(uD.x);
        a2 += fp8_fv2<false>(uD.y); a3 += fp8_fv2<true>(uD.y);
    }
    for (; k < p1; ++k) {
        int j = col[k];
        uint2 u = hrow[(size_t)j * 16 + l];
        a0 += fp8_fv2<false>(u.x); a1 += fp8_fv2<true>(u.x);
        a2 += fp8_fv2<false>(u.y); a3 += fp8_fv2<true>(u.y);
    }
    // epilogue: every lane finalizes its own 8 columns (4 nodes per wave)
    float di = dinv[node];
    float4 b4a = *(const float4*)(bias + 8 * l);
    float4 b4b = *(const float4*)(bias + 8 * l + 4);
    float v0 = fmaf(di, a0.x, b4a.x);
    float v1 = fmaf(di, a0.y, b4a.y);
    float v2 = fmaf(di, a1.x, b4a.z);
    float v3 = fmaf(di, a1.y, b4a.w);
    float v4 = fmaf(di, a2.x, b4b.x);
    float v5 = fmaf(di, a2.y, b4b.y);
    float v6 = fmaf(di, a3.x, b4b.z);
    float v7 = fmaf(di, a3.y, b4b.w);
    v0 = v0 > 0.f ? v0 : 0.f;
    v1 = v1 > 0.f ? v1 : 0.f;
    v2 = v2 > 0.f ? v2 : 0.f;
    v3 = v3 > 0.f ? v3 : 0.f;
    v4 = v4 > 0.f ? v4 : 0.f;
    v5 = v5 > 0.f ? v5 : 0.f;
    v6 = v6 > 0.f ? v6 : 0.f;
    v7 = v7 > 0.f ? v7 : 0.f;
    uint4 o = {pack_bf16x2(v0, v1), pack_bf16x2(v2, v3),
               pack_bf16x2(v4, v5), pack_bf16x2(v6, v7)};
    *(uint4*)(out + (size_t)node * 64 + 4 * l) = o;
}

// Layer 2: hs rows = 16 uint2 (64 bf16). Lane owns bf16 cols 4l..4l+3.
// Fused log_softmax: 16-lane reduce (xor offsets 1..8 stay inside the quarter).
__global__ __launch_bounds__(256) void k_agg_lsm(const unsigned* __restrict__ hs,
                                                 const float* __restrict__ dinv,
                                                 const int* __restrict__ row_ptr,
                                                 const int* __restrict__ col,
                                                 const float* __restrict__ bias,
                                                 float* __restrict__ out, int n) {
    int node = blockIdx.x * 16 + (threadIdx.x >> 4);
    if (node >= n) return;
    int l = threadIdx.x & 15;
    const uint2* hrow = (const uint2*)hs;
    fv2 aX = {0.f, 0.f}, aY = {0.f, 0.f};
    {   // self term
        uint2 u = hrow[(size_t)node * 16 + l];
        aX += bfpair(u.x);
        aY += bfpair(u.y);
    }
    int k = row_ptr[node], p1 = row_ptr[node + 1];
    for (; k + 8 <= p1; k += 8) {
        int cA = col[k + 0], cB = col[k + 1], cC = col[k + 2], cD = col[k + 3];
        int cE = col[k + 4], cF = col[k + 5], cG = col[k + 6], cH = col[k + 7];
        uint2 uA = hrow[(size_t)cA * 16 + l];
        uint2 uB = hrow[(size_t)cB * 16 + l];
        uint2 uC = hrow[(size_t)cC * 16 + l];
        uint2 uD = hrow[(size_t)cD * 16 + l];
        uint2 uE = hrow[(size_t)cE * 16 + l];
        uint2 uF = hrow[(size_t)cF * 16 + l];
        uint2 uG = hrow[(size_t)cG * 16 + l];
        uint2 uH = hrow[(size_t)cH * 16 + l];
        aX += bfpair(uA.x); aY += bfpair(uA.y);
        aX += bfpair(uB.x); aY += bfpair(uB.y);
        aX += bfpair(uC.x); aY += bfpair(uC.y);
        aX += bfpair(uD.x); aY += bfpair(uD.y);
        aX += bfpair(uE.x); aY += bfpair(uE.y);
        aX += bfpair(uF.x); aY += bfpair(uF.y);
        aX += bfpair(uG.x); aY += bfpair(uG.y);
        aX += bfpair(uH.x); aY += bfpair(uH.y);
    }
    for (; k + 4 <= p1; k += 4) {
        int cA = col[k + 0], cB = col[k + 1], cC = col[k + 2], cD = col[k + 3];
        uint2 uA = hrow[(size_t)cA * 16 + l];
        uint2 uB = hrow[(size_t)cB * 16 + l];
        uint2 uC = hrow[(size_t)cC * 16 + l];
        uint2 uD = hrow[(size_t)cD * 16 + l];
        aX += bfpair(uA.x); aY += bfpair(uA.y);
        aX += bfpair(uB.x); aY += bfpair(uB.y);
        aX += bfpair(uC.x); aY += bfpair(uC.y);
        aX += bfpair(uD.x); aY += bfpair(uD.y);
    }
    for (; k < p1; ++k) {
        int j = col[k];
        uint2 u = hrow[(size_t)j * 16 + l];
        aX += bfpair(u.x); aY += bfpair(u.y);
    }
    float di = dinv[node];
    float4 b4 = *(const float4*)(bias + 4 * l);
    float v0 = fmaf(di, aX.x, b4.x);
    float v1 = fmaf(di, aX.y, b4.y);
    float v2 = fmaf(di, aY.x, b4.z);
    float v3 = fmaf(di, aY.y, b4.w);
    float m = fmaxf(fmaxf(v0, v1), fmaxf(v2, v3));
    for (int off = 8; off; off >>= 1) m = fmaxf(m, __shfl_xor(m, off));
    float s = __expf(v0 - m) + __expf(v1 - m) + __expf(v2 - m) + __expf(v3 - m);
    for (int off = 8; off; off >>= 1) s += __shfl_xor(s, off);
    float ls = __logf(s);
    float4 o = {v0 - m - ls, v1 - m - ls, v2 - m - ls, v3 - m - ls};
    *(float4*)(out + (size_t)node * 64 + 4 * l) = o;
}

// ---------------- launcher ----------------

extern "C" void kernel_launch(void* const* d_in, const int* in_sizes, int n_in,
                              void* d_out, int out_size, void* d_ws, size_t ws_size,
                              hipStream_t stream) {
    const float* x  = (const float*)d_in[0];
    const int*   ei = (const int*)d_in[1];
    const float* W1 = (const float*)d_in[2];
    const float* b1 = (const float*)d_in[3];
    const float* W2 = (const float*)d_in[4];
    const float* b2 = (const float*)d_in[5];
    float* out = (float*)d_out;

    const int N = in_sizes[0] / 128;   // 100000
    const int E = in_sizes[1] / 2;     // 1600000
    const int* src = ei;
    const int* dst = ei + E;
    const int npp = (N + NPART - 1) / NPART;           // 12500
    const int capE = (E + NPART - 1) / NPART + 32768;  // segment capacity + slack
    int srcb = 1;
    while ((1 << srcb) < N) ++srcb;                    // 17 for N=100000

    char* w = (char*)d_ws;
    size_t off = 0;
    auto alloc = [&](size_t bytes) -> void* {
        void* p = w + off;
        off += (bytes + 255) & ~(size_t)255;
        return p;
    };
    int*      row_ptr  = (int*)alloc((size_t)(N + 1) * 4);
    int*      colarr   = (int*)alloc((size_t)E * 4);
    int*      gpart    = (int*)alloc(256 * 4);
    int*      cursor8  = (int*)alloc(8 * 4);
    int*      bar      = (int*)alloc(16 * 4);
    float*    dinv     = (float*)alloc((size_t)N * 4);
    unsigned* h1f8     = (unsigned*)alloc((size_t)N * 32 * 4);  // fp8 X@W1 scaled
    unsigned* a1b      = (unsigned*)alloc((size_t)N * 64 * 4);  // bf16 relu out
    unsigned* h2b      = (unsigned*)alloc((size_t)N * 32 * 4);  // bf16 a1@W2 scaled
    unsigned* Bp1      = (unsigned*)alloc(4 * 8 * 64 * 16);     // W1 frag stream 32KB
    unsigned* Bp2      = (unsigned*)alloc(4 * 4 * 64 * 16);     // W2 frag stream 16KB
    // pairs (7.5 MB) + cntarr (12.8 MB) alias a1b (25.6 MB), dead before agg_relu
    unsigned* pairsU   = (unsigned*)a1b;
    int*      cntarr   = (int*)((char*)a1b + (size_t)NPART * capE * 4);
    (void)ws_size; (void)n_in; (void)out_size;

    int nscan = (N + 1023) / 1024;
    int ngemm = (N + 63) / 64;

    k_packW2<<<2, 256, 0, stream>>>(W1, Bp1, W2, Bp2, cursor8, bar);
    k_mega_csr<<<256, 256, 0, stream>>>(src, dst, cursor8, pairsU, cntarr, dinv,
                                        row_ptr, gpart, bar, colarr,
                                        E, N, npp, capE, srcb, nscan);
    k_gemm128_mfma<<<ngemm, 256, 0, stream>>>(x, Bp1, dinv, (unsigned char*)h1f8, N);
    k_agg_relu<<<(N + 15) / 16, 256, 0, stream>>>(h1f8, dinv, row_ptr, colarr, b1, a1b, N);
    k_gemm64_mfma<<<ngemm, 256, 0, stream>>>(a1b, Bp2, dinv, (unsigned short*)h2b, N);
    k_agg_lsm<<<(N + 15) / 16, 256, 0, stream>>>(h2b, dinv, row_ptr, colarr, b2, out, N);
}

// Round 8
// 264.516 us; speedup vs baseline: 1.5296x; 1.5296x over previous
//
#include <hip/hip_runtime.h>
#include <hip/hip_fp16.h>
#include <cstdint>
#include <cstddef>
#include <cstring>

// ---------------- bf16 pack/unpack helpers (RNE) ----------------

__device__ inline unsigned pack_bf16x2(float a, float b) {
    unsigned ua = __float_as_uint(a);
    unsigned ub = __float_as_uint(b);
    ua += 0x7fffu + ((ua >> 16) & 1u);
    ub += 0x7fffu + ((ub >> 16) & 1u);
    return (ua >> 16) | (ub & 0xffff0000u);
}
__device__ inline unsigned short bf16_rne(float v) {
    unsigned u = __float_as_uint(v);
    u += 0x7fffu + ((u >> 16) & 1u);
    return (unsigned short)(u >> 16);
}

// ---------------- fp8 (OCP e4m3fn) pack/unpack ----------------

typedef float fv2 __attribute__((ext_vector_type(2)));

template <bool HI>
__device__ inline fv2 fp8_fv2(unsigned u) {
#if __has_builtin(__builtin_amdgcn_cvt_pk_f32_fp8)
    return __builtin_amdgcn_cvt_pk_f32_fp8((int)u, HI);
#else
    unsigned u2 = HI ? (u >> 16) : (u & 0xffffu);
    unsigned w = (u2 & 0xFFu) | ((u2 & 0xFF00u) << 8);
    unsigned hb = ((w & 0x00800080u) << 8) | ((w & 0x007f007fu) << 7);
    __half2 h2;
    memcpy(&h2, &hb, 4);
    float2 f = __half22float2(h2);
    fv2 r;
    r.x = f.x * 256.0f;
    r.y = f.y * 256.0f;
    return r;
#endif
}

// bf16 pair (packed in a uint) -> fv2  (2 bitops, then packed add on use)
__device__ inline fv2 bfpair(unsigned u) {
    union { unsigned q[2]; fv2 f; } t;
    t.q[0] = u << 16;
    t.q[1] = u & 0xffff0000u;
    return t.f;
}

__device__ inline unsigned f32_to_fp8_byte(float v) {
    unsigned short hb = __half_as_ushort(__float2half(v * 0.00390625f));  // v/256
    unsigned t = hb & 0x7fffu;
    t += 0x3fu + ((t >> 7) & 1u);
    return ((hb >> 8) & 0x80u) | (t >> 7);
}

__device__ inline unsigned char f32_to_fp8_b(float v) {
#if __has_builtin(__builtin_amdgcn_cvt_pk_fp8_f32)
    return (unsigned char)(__builtin_amdgcn_cvt_pk_fp8_f32(v, v, 0, false) & 0xff);
#else
    return (unsigned char)f32_to_fp8_byte(v);
#endif
}

typedef int iv4 __attribute__((ext_vector_type(4)));

#define NPART 8
#define KB    32
#define NPP_MAX 12500
#define EB    2048   // edges per bucket block (8 per thread)

// ---------------- CSR build (R6-proven chain, reverted from R7 mega) --------
// R7 lesson: fusing the chain into one co-resident kernel pinned every phase
// at 1 block/CU (51KB LDS) -> 4 waves/CU for latency-bound phases = 2x SLOWER.
// Kernel boundaries cost ~1us each (R2->R6 calibration); chained kernels let
// each phase run at its own occupancy. Keep the chain.
//  - R3: col scatter-writes confined to L2-sized windows (no amplification)
//  - R5: never issue per-edge global atomics (coherence-point traffic)
//  - R6: ballot bucket -- zero per-edge atomics, 8 global atomics per block

__global__ __launch_bounds__(256) void k_bucket_ballot(const int* __restrict__ src,
                                                       const int* __restrict__ dst,
                                                       int* __restrict__ cursor8,
                                                       unsigned* __restrict__ pairs,
                                                       int E, int npp, int capE,
                                                       int srcb) {
    __shared__ int sWcnt[4][NPART];
    __shared__ int sWoff[4][NPART];
    int tid = threadIdx.x;
    int wv = tid >> 6;
    int lane = tid & 63;
    int base_e = blockIdx.x * EB + tid * 8;
    int nv = min(8, E - base_e);
    if (nv < 0) nv = 0;
    int dv[8], sv[8];
    if (nv == 8) {
        *(iv4*)(dv + 0) = *(const iv4*)(dst + base_e + 0);
        *(iv4*)(dv + 4) = *(const iv4*)(dst + base_e + 4);
        *(iv4*)(sv + 0) = *(const iv4*)(src + base_e + 0);
        *(iv4*)(sv + 4) = *(const iv4*)(src + base_e + 4);
    } else {
        for (int k = 0; k < 8; ++k) {
            dv[k] = (k < nv) ? dst[base_e + k] : -1;
            sv[k] = (k < nv) ? src[base_e + k] : 0;
        }
    }
    unsigned long long below = (1ull << lane) - 1ull;
    int wb[NPART];
#pragma unroll
    for (int pp = 0; pp < NPART; ++pp) wb[pp] = 0;
    int pv[8], pos[8];
#pragma unroll
    for (int s = 0; s < 8; ++s) {
        int d = dv[s];
        int p = (d >= 0) ? (int)((unsigned)d / (unsigned)npp) : NPART;
        pv[s] = p;
        unsigned long long msel = 0;
        int base = 0;
#pragma unroll
        for (int pp = 0; pp < NPART; ++pp) {
            unsigned long long m = __ballot(p == pp);
            if (p == pp) { msel = m; base = wb[pp]; }
            wb[pp] += (int)__popcll(m);   // ballot result is wave-uniform
        }
        pos[s] = base + (int)__popcll(msel & below);
    }
    // wave totals -> LDS (static indexing to keep wb in registers)
    if (lane < NPART) {
        int v = 0;
#pragma unroll
        for (int pp = 0; pp < NPART; ++pp)
            if (lane == pp) v = wb[pp];
        sWcnt[wv][lane] = v;
    }
    __syncthreads();
    if (tid < NPART) {
        int c0 = sWcnt[0][tid], c1 = sWcnt[1][tid], c2 = sWcnt[2][tid], c3 = sWcnt[3][tid];
        int gb = atomicAdd(&cursor8[tid], c0 + c1 + c2 + c3);  // 8 atomics/block
        sWoff[0][tid] = gb;
        sWoff[1][tid] = gb + c0;
        sWoff[2][tid] = gb + c0 + c1;
        sWoff[3][tid] = gb + c0 + c1 + c2;
    }
    __syncthreads();
#pragma unroll
    for (int s = 0; s < 8; ++s) {
        int p = pv[s];
        if (p < NPART) {
            int off = sWoff[wv][p];
            pairs[(size_t)p * capE + off + pos[s]] =
                ((unsigned)(dv[s] - p * npp) << srcb) | (unsigned)sv[s];
        }
    }
}

__global__ __launch_bounds__(256) void k_count_part(const unsigned* __restrict__ pairs,
                                                    const int* __restrict__ cursor8,
                                                    int* __restrict__ cntarr,
                                                    int npp, int capE, int srcb) {
    __shared__ int h[NPP_MAX];
    int p = blockIdx.x & (NPART - 1);
    int b = blockIdx.x >> 3;
    for (int i = threadIdx.x; i < npp; i += 256) h[i] = 0;
    __syncthreads();
    int sz = cursor8[p];
    int chunk = (sz + KB - 1) / KB;
    int s0 = b * chunk;
    int s1 = min(sz, s0 + chunk);
    const unsigned* seg = pairs + (size_t)p * capE;
    for (int i = s0 + threadIdx.x; i < s1; i += 256)
        atomicAdd(&h[seg[i] >> srcb], 1);
    __syncthreads();
    size_t out = (size_t)(p * KB + b) * npp;
    for (int i = threadIdx.x; i < npp; i += 256) cntarr[out + i] = h[i];
}

// Fused: per-node degree (sum of 32 cntarr slices) -> dinv + block-local scan.
__global__ void k_indeg_scan(const int* __restrict__ cntarr,
                             float* __restrict__ dinv,
                             int* __restrict__ row_ptr,
                             int* __restrict__ partials, int n, int npp) {
    __shared__ int s[256];
    int t = threadIdx.x;
    int node0 = blockIdx.x * 1024 + t * 4;
    int v0 = 0, v1 = 0, v2 = 0, v3 = 0;
    if (((npp & 3) == 0) && (node0 + 3 < n) && (node0 / npp == (node0 + 3) / npp)) {
        int p = node0 / npp;
        int dl = node0 - p * npp;
        size_t base = (size_t)p * KB * npp + dl;
        for (int b = 0; b < KB; ++b) {
            iv4 c = *(const iv4*)(cntarr + base + (size_t)b * npp);
            v0 += c.x; v1 += c.y; v2 += c.z; v3 += c.w;
        }
    } else {
        for (int r = 0; r < 4; ++r) {
            int node = node0 + r;
            if (node < n) {
                int p = node / npp;
                int dl = node - p * npp;
                size_t base = (size_t)p * KB * npp + dl;
                int sum = 0;
                for (int b = 0; b < KB; ++b) sum += cntarr[base + (size_t)b * npp];
                if (r == 0) v0 = sum; else if (r == 1) v1 = sum;
                else if (r == 2) v2 = sum; else v3 = sum;
            }
        }
    }
    if (node0 + 0 < n) dinv[node0 + 0] = rsqrtf((float)v0 + 1.0f);
    if (node0 + 1 < n) dinv[node0 + 1] = rsqrtf((float)v1 + 1.0f);
    if (node0 + 2 < n) dinv[node0 + 2] = rsqrtf((float)v2 + 1.0f);
    if (node0 + 3 < n) dinv[node0 + 3] = rsqrtf((float)v3 + 1.0f);
    int sum = v0 + v1 + v2 + v3;
    s[t] = sum;
    __syncthreads();
    for (int off = 1; off < 256; off <<= 1) {
        int x = (t >= off) ? s[t - off] : 0;
        __syncthreads();
        s[t] += x;
        __syncthreads();
    }
    int excl = s[t] - sum;
    if ((node0 + 0) < n) row_ptr[node0 + 0] = excl;
    if ((node0 + 1) < n) row_ptr[node0 + 1] = excl + v0;
    if ((node0 + 2) < n) row_ptr[node0 + 2] = excl + v0 + v1;
    if ((node0 + 3) < n) row_ptr[node0 + 3] = excl + v0 + v1 + v2;
    if (t == 255) partials[blockIdx.x] = s[255];
}

__global__ void k_scan_partials(int* __restrict__ partials, int np) {
    __shared__ int s[256];
    int t = threadIdx.x;
    int v = (t < np) ? partials[t] : 0;
    s[t] = v;
    __syncthreads();
    for (int off = 1; off < 256; off <<= 1) {
        int x = (t >= off) ? s[t - off] : 0;
        __syncthreads();
        s[t] += x;
        __syncthreads();
    }
    if (t < np) partials[t] = s[t] - v;
}

// Fused: row_ptr fixup + per-slice base rewrite (cntarr becomes fill cursors).
__global__ void k_finalize_bases(int* __restrict__ row_ptr,
                                 const int* __restrict__ partials,
                                 int* __restrict__ cntarr, int n, int E, int npp) {
    int i = blockIdx.x * blockDim.x + threadIdx.x;
    if (i >= n) return;
    int rp = row_ptr[i] + partials[i >> 10];
    row_ptr[i] = rp;
    if (i == 0) row_ptr[n] = E;
    int p = (unsigned)i / (unsigned)npp;
    int dl = i - p * npp;
    size_t base = (size_t)p * KB * npp + dl;
    int run = rp;
    for (int b = 0; b < KB; ++b) {
        size_t idx = base + (size_t)b * npp;
        int c = cntarr[idx];
        cntarr[idx] = run;
        run += c;
    }
}

__global__ __launch_bounds__(256) void k_fill2(const unsigned* __restrict__ pairs,
                                               const int* __restrict__ cursor8,
                                               const int* __restrict__ cntarr,
                                               int* __restrict__ col,
                                               int npp, int capE, int srcb) {
    __shared__ int cur[NPP_MAX];
    int p = blockIdx.x & (NPART - 1);
    int b = blockIdx.x >> 3;
    size_t slice = (size_t)(p * KB + b) * npp;
    for (int i = threadIdx.x; i < npp; i += 256) cur[i] = cntarr[slice + i];
    __syncthreads();
    int sz = cursor8[p];
    int chunk = (sz + KB - 1) / KB;
    int s0 = b * chunk;
    int s1 = min(sz, s0 + chunk);
    const unsigned* seg = pairs + (size_t)p * capE;
    unsigned smask = (1u << srcb) - 1u;
    for (int i = s0 + threadIdx.x; i < s1; i += 256) {
        unsigned u = seg[i];
        int pos = atomicAdd(&cur[u >> srcb], 1);
        col[pos] = (int)(u & smask);
    }
}

// ---------------- MFMA GEMMs ----------------
typedef __attribute__((ext_vector_type(8))) short short8;
typedef __attribute__((ext_vector_type(4))) float f32x4;

union FragU {
    short8 s;
    uint4 u4;
    unsigned u[4];
};

__device__ inline void packW_body(const float* __restrict__ W, unsigned* __restrict__ Bp,
                                  int NOUT, int NT) {
    int nf = 4 * NT * 64;
    for (int fid = threadIdx.x; fid < nf; fid += 256) {
        int q = fid / (NT * 64);
        int rem = fid - q * NT * 64;
        int nt = rem >> 6;
        int lane = rem & 63;
        int k0 = q * 32 + (lane >> 4) * 8;
        int ncol = nt * 16 + (lane & 15);
        unsigned u[4];
        for (int h = 0; h < 4; ++h) {
            float a = W[(k0 + 2 * h) * NOUT + ncol];
            float b = W[(k0 + 2 * h + 1) * NOUT + ncol];
            u[h] = pack_bf16x2(a, b);
        }
        uint4 o = {u[0], u[1], u[2], u[3]};
        *(uint4*)(Bp + (size_t)fid * 4) = o;
    }
}

// both weight packs in one dispatch (block 0 -> W1, block 1 -> W2)
__global__ void k_packW2(const float* __restrict__ W1, unsigned* __restrict__ Bp1,
                         const float* __restrict__ W2, unsigned* __restrict__ Bp2) {
    if (blockIdx.x == 0) packW_body(W1, Bp1, 128, 8);
    else                 packW_body(W2, Bp2, 64, 4);
}

__global__ __launch_bounds__(256) void k_gemm128_mfma(const float* __restrict__ X,
                                                      const unsigned* __restrict__ Bp,
                                                      const float* __restrict__ dinv,
                                                      unsigned char* __restrict__ H8,
                                                      int n) {
    int w = threadIdx.x >> 6;
    int lane = threadIdx.x & 63;
    int quad = lane >> 4;
    int lrow = lane & 15;
    int row0 = blockIdx.x * 64 + w * 16;
    int rowA = min(row0 + lrow, n - 1);

    f32x4 acc[8];
    for (int nt = 0; nt < 8; ++nt) acc[nt] = (f32x4){0.f, 0.f, 0.f, 0.f};

    for (int q = 0; q < 4; ++q) {
        const float* xp = X + (size_t)rowA * 128 + q * 32 + quad * 8;
        float4 x0 = *(const float4*)xp;
        float4 x1 = *(const float4*)(xp + 4);
        FragU a;
        a.u[0] = pack_bf16x2(x0.x, x0.y);
        a.u[1] = pack_bf16x2(x0.z, x0.w);
        a.u[2] = pack_bf16x2(x1.x, x1.y);
        a.u[3] = pack_bf16x2(x1.z, x1.w);
        for (int nt = 0; nt < 8; ++nt) {
            FragU b;
            b.u4 = *(const uint4*)(Bp + ((size_t)(q * 8 + nt) * 64 + lane) * 4);
            acc[nt] = __builtin_amdgcn_mfma_f32_16x16x32_bf16(a.s, b.s, acc[nt], 0, 0, 0);
        }
    }

    int rbase = row0 + quad * 4;
    float dv[4];
    if (rbase + 3 < n) {
        float4 d4 = *(const float4*)(dinv + rbase);
        dv[0] = d4.x; dv[1] = d4.y; dv[2] = d4.z; dv[3] = d4.w;
    } else {
        for (int r = 0; r < 4; ++r) dv[r] = dinv[min(rbase + r, n - 1)];
    }
    for (int nt = 0; nt < 8; ++nt) {
        for (int r = 0; r < 4; ++r) {
            int row = rbase + r;
            if (row < n)
                H8[(size_t)row * 128 + nt * 16 + lrow] = f32_to_fp8_b(dv[r] * acc[nt][r]);
        }
    }
}

// ---------------- Layer-1 aggregation FUSED with the W2 GEMM ----------------
// R13-proven agg structure (quarter-wave per node) + in-block 16x128 @ 128x64
// MFMA epilogue. Deletes the a1b intermediate entirely (25.6MB write + 25.6MB
// read) and the separate gemm64 dispatch. LDS tile is 16 rows x 68-uint pitch
// (pad 64->68 breaks the stride-64 bank collision to a free 2-way).
__global__ __launch_bounds__(256) void k_agg_relu_gemm(const unsigned* __restrict__ hs,
                                                       const float* __restrict__ dinv,
                                                       const int* __restrict__ row_ptr,
                                                       const int* __restrict__ col,
                                                       const float* __restrict__ bias,
                                                       const unsigned* __restrict__ Bp2,
                                                       unsigned short* __restrict__ H16,
                                                       int n) {
    __shared__ unsigned s_a[16][68];
    int q16 = threadIdx.x >> 4;                 // local node 0..15
    int node = blockIdx.x * 16 + q16;
    int l = threadIdx.x & 15;
    bool alive = node < n;
    int nodeC = alive ? node : (n - 1);
    const uint2* hrow = (const uint2*)hs;
    fv2 a0 = {0.f, 0.f}, a1 = {0.f, 0.f}, a2 = {0.f, 0.f}, a3 = {0.f, 0.f};
    if (alive) {   // self term
        uint2 u = hrow[(size_t)node * 16 + l];
        a0 += fp8_fv2<false>(u.x); a1 += fp8_fv2<true>(u.x);
        a2 += fp8_fv2<false>(u.y); a3 += fp8_fv2<true>(u.y);
    }
    int k = alive ? row_ptr[node] : 0;
    int p1 = alive ? row_ptr[node + 1] : 0;
    for (; k + 8 <= p1; k += 8) {  // 8 edges/quarter, 8 loads in flight/lane
        int cA = col[k + 0], cB = col[k + 1], cC = col[k + 2], cD = col[k + 3];
        int cE = col[k + 4], cF = col[k + 5], cG = col[k + 6], cH = col[k + 7];
        uint2 uA = hrow[(size_t)cA * 16 + l];
        uint2 uB = hrow[(size_t)cB * 16 + l];
        uint2 uC = hrow[(size_t)cC * 16 + l];
        uint2 uD = hrow[(size_t)cD * 16 + l];
        uint2 uE = hrow[(size_t)cE * 16 + l];
        uint2 uF = hrow[(size_t)cF * 16 + l];
        uint2 uG = hrow[(size_t)cG * 16 + l];
        uint2 uH = hrow[(size_t)cH * 16 + l];
        a0 += fp8_fv2<false>(uA.x); a1 += fp8_fv2<true>(uA.x);
        a2 += fp8_fv2<false>(uA.y); a3 += fp8_fv2<true>(uA.y);
        a0 += fp8_fv2<false>(uB.x); a1 += fp8_fv2<true>(uB.x);
        a2 += fp8_fv2<false>(uB.y); a3 += fp8_fv2<true>(uB.y);
        a0 += fp8_fv2<false>(uC.x); a1 += fp8_fv2<true>(uC.x);
        a2 += fp8_fv2<false>(uC.y); a3 += fp8_fv2<true>(uC.y);
        a0 += fp8_fv2<false>(uD.x); a1 += fp8_fv2<true>(uD.x);
        a2 += fp8_fv2<false>(uD.y); a3 += fp8_fv2<true>(uD.y);
        a0 += fp8_fv2<false>(uE.x); a1 += fp8_fv2<true>(uE.x);
        a2 += fp8_fv2<false>(uE.y); a3 += fp8_fv2<true>(uE.y);
        a0 += fp8_fv2<false>(uF.x); a1 += fp8_fv2<true>(uF.x);
        a2 += fp8_fv2<false>(uF.y); a3 += fp8_fv2<true>(uF.y);
        a0 += fp8_fv2<false>(uG.x); a1 += fp8_fv2<true>(uG.x);
        a2 += fp8_fv2<false>(uG.y); a3 += fp8_fv2<true>(uG.y);
        a0 += fp8_fv2<false>(uH.x); a1 += fp8_fv2<true>(uH.x);
        a2 += fp8_fv2<false>(uH.y); a3 += fp8_fv2<true>(uH.y);
    }
    for (; k + 4 <= p1; k += 4) {
        int cA = col[k + 0], cB = col[k + 1], cC = col[k + 2], cD = col[k + 3];
        uint2 uA = hrow[(size_t)cA * 16 + l];
        uint2 uB = hrow[(size_t)cB * 16 + l];
        uint2 uC = hrow[(size_t)cC * 16 + l];
        uint2 uD = hrow[(size_t)cD * 16 + l];
        a0 += fp8_fv2<false>(uA.x); a1 += fp8_fv2<true>(uA.x);
        a2 += fp8_fv2<false>(uA.y); a3 += fp8_fv2<true>(uA.y);
        a0 += fp8_fv2<false>(uB.x); a1 += fp8_fv2<true>(uB.x);
        a2 += fp8_fv2<false>(uB.y); a3 += fp8_fv2<true>(uB.y);
        a0 += fp8_fv2<false>(uC.x); a1 += fp8_fv2<true>(uC.x);
        a2 += fp8_fv2<false>(uC.y); a3 += fp8_fv2<true>(uC.y);
        a0 += fp8_fv2<false>(uD.x); a1 += fp8_fv2<true>(uD.x);
        a2 += fp8_fv2<false>(uD.y); a3 += fp8_fv2<true>(uD.y);
    }
    for (; k < p1; ++k) {
        int j = col[k];
        uint2 u = hrow[(size_t)j * 16 + l];
        a0 += fp8_fv2<false>(u.x); a1 += fp8_fv2<true>(u.x);
        a2 += fp8_fv2<false>(u.y); a3 += fp8_fv2<true>(u.y);
    }
    // epilogue: every lane finalizes its own 8 columns -> bf16 into LDS tile
    {
        float di = dinv[nodeC];
        float4 b4a = *(const float4*)(bias + 8 * l);
        float4 b4b = *(const float4*)(bias + 8 * l + 4);
        float v0 = fmaf(di, a0.x, b4a.x);
        float v1 = fmaf(di, a0.y, b4a.y);
        float v2 = fmaf(di, a1.x, b4a.z);
        float v3 = fmaf(di, a1.y, b4a.w);
        float v4 = fmaf(di, a2.x, b4b.x);
        float v5 = fmaf(di, a2.y, b4b.y);
        float v6 = fmaf(di, a3.x, b4b.z);
        float v7 = fmaf(di, a3.y, b4b.w);
        v0 = v0 > 0.f ? v0 : 0.f;
        v1 = v1 > 0.f ? v1 : 0.f;
        v2 = v2 > 0.f ? v2 : 0.f;
        v3 = v3 > 0.f ? v3 : 0.f;
        v4 = v4 > 0.f ? v4 : 0.f;
        v5 = v5 > 0.f ? v5 : 0.f;
        v6 = v6 > 0.f ? v6 : 0.f;
        v7 = v7 > 0.f ? v7 : 0.f;
        uint4 o = {pack_bf16x2(v0, v1), pack_bf16x2(v2, v3),
                   pack_bf16x2(v4, v5), pack_bf16x2(v6, v7)};
        *(uint4*)&s_a[q16][4 * l] = o;
    }
    __syncthreads();
    // W2 GEMM: 16 nodes x 128 @ 128 x 64. Wave w owns N-tile nt=w (16 cols).
    // Fragment layouts identical to the standalone gemm64 (A: row=lane&15,
    // k-chunk=q*16+4*quad uints; C: row=quad*4+r, col=nt*16+(lane&15)).
    {
        int lane = threadIdx.x & 63;
        int w = threadIdx.x >> 6;
        int quad = lane >> 4;
        int lrow = lane & 15;
        f32x4 acc = (f32x4){0.f, 0.f, 0.f, 0.f};
        for (int q = 0; q < 4; ++q) {
            FragU a, b;
            a.u4 = *(const uint4*)&s_a[lrow][16 * q + 4 * quad];
            b.u4 = *(const uint4*)(Bp2 + ((size_t)(q * 4 + w) * 64 + lane) * 4);
            acc = __builtin_amdgcn_mfma_f32_16x16x32_bf16(a.s, b.s, acc, 0, 0, 0);
        }
        int rbase = blockIdx.x * 16 + quad * 4;
        for (int r = 0; r < 4; ++r) {
            int nd = rbase + r;
            if (nd < n)
                H16[(size_t)nd * 64 + w * 16 + lrow] = bf16_rne(dinv[nd] * acc[r]);
        }
    }
}

// Layer 2: hs rows = 16 uint2 (64 bf16). Lane owns bf16 cols 4l..4l+3.
// Fused log_softmax: 16-lane reduce (xor offsets 1..8 stay inside the quarter).
__global__ __launch_bounds__(256) void k_agg_lsm(const unsigned* __restrict__ hs,
                                                 const float* __restrict__ dinv,
                                                 const int* __restrict__ row_ptr,
                                                 const int* __restrict__ col,
                                                 const float* __restrict__ bias,
                                                 float* __restrict__ out, int n) {
    int node = blockIdx.x * 16 + (threadIdx.x >> 4);
    if (node >= n) return;
    int l = threadIdx.x & 15;
    const uint2* hrow = (const uint2*)hs;
    fv2 aX = {0.f, 0.f}, aY = {0.f, 0.f};
    {   // self term
        uint2 u = hrow[(size_t)node * 16 + l];
        aX += bfpair(u.x);
        aY += bfpair(u.y);
    }
    int k = row_ptr[node], p1 = row_ptr[node + 1];
    for (; k + 8 <= p1; k += 8) {
        int cA = col[k + 0], cB = col[k + 1], cC = col[k + 2], cD = col[k + 3];
        int cE = col[k + 4], cF = col[k + 5], cG = col[k + 6], cH = col[k + 7];
        uint2 uA = hrow[(size_t)cA * 16 + l];
        uint2 uB = hrow[(size_t)cB * 16 + l];
        uint2 uC = hrow[(size_t)cC * 16 + l];
        uint2 uD = hrow[(size_t)cD * 16 + l];
        uint2 uE = hrow[(size_t)cE * 16 + l];
        uint2 uF = hrow[(size_t)cF * 16 + l];
        uint2 uG = hrow[(size_t)cG * 16 + l];
        uint2 uH = hrow[(size_t)cH * 16 + l];
        aX += bfpair(uA.x); aY += bfpair(uA.y);
        aX += bfpair(uB.x); aY += bfpair(uB.y);
        aX += bfpair(uC.x); aY += bfpair(uC.y);
        aX += bfpair(uD.x); aY += bfpair(uD.y);
        aX += bfpair(uE.x); aY += bfpair(uE.y);
        aX += bfpair(uF.x); aY += bfpair(uF.y);
        aX += bfpair(uG.x); aY += bfpair(uG.y);
        aX += bfpair(uH.x); aY += bfpair(uH.y);
    }
    for (; k + 4 <= p1; k += 4) {
        int cA = col[k + 0], cB = col[k + 1], cC = col[k + 2], cD = col[k + 3];
        uint2 uA = hrow[(size_t)cA * 16 + l];
        uint2 uB = hrow[(size_t)cB * 16 + l];
        uint2 uC = hrow[(size_t)cC * 16 + l];
        uint2 uD = hrow[(size_t)cD * 16 + l];
        aX += bfpair(uA.x); aY += bfpair(uA.y);
        aX += bfpair(uB.x); aY += bfpair(uB.y);
        aX += bfpair(uC.x); aY += bfpair(uC.y);
        aX += bfpair(uD.x); aY += bfpair(uD.y);
    }
    for (; k < p1; ++k) {
        int j = col[k];
        uint2 u = hrow[(size_t)j * 16 + l];
        aX += bfpair(u.x); aY += bfpair(u.y);
    }
    float di = dinv[node];
    float4 b4 = *(const float4*)(bias + 4 * l);
    float v0 = fmaf(di, aX.x, b4.x);
    float v1 = fmaf(di, aX.y, b4.y);
    float v2 = fmaf(di, aY.x, b4.z);
    float v3 = fmaf(di, aY.y, b4.w);
    float m = fmaxf(fmaxf(v0, v1), fmaxf(v2, v3));
    for (int off = 8; off; off >>= 1) m = fmaxf(m, __shfl_xor(m, off));
    float s = __expf(v0 - m) + __expf(v1 - m) + __expf(v2 - m) + __expf(v3 - m);
    for (int off = 8; off; off >>= 1) s += __shfl_xor(s, off);
    float ls = __logf(s);
    float4 o = {v0 - m - ls, v1 - m - ls, v2 - m - ls, v3 - m - ls};
    *(float4*)(out + (size_t)node * 64 + 4 * l) = o;
}

// ---------------- launcher ----------------

extern "C" void kernel_launch(void* const* d_in, const int* in_sizes, int n_in,
                              void* d_out, int out_size, void* d_ws, size_t ws_size,
                              hipStream_t stream) {
    const float* x  = (const float*)d_in[0];
    const int*   ei = (const int*)d_in[1];
    const float* W1 = (const float*)d_in[2];
    const float* b1 = (const float*)d_in[3];
    const float* W2 = (const float*)d_in[4];
    const float* b2 = (const float*)d_in[5];
    float* out = (float*)d_out;

    const int N = in_sizes[0] / 128;   // 100000
    const int E = in_sizes[1] / 2;     // 1600000
    const int* src = ei;
    const int* dst = ei + E;
    const int npp = (N + NPART - 1) / NPART;           // 12500
    const int capE = (E + NPART - 1) / NPART + 32768;  // segment capacity + slack
    int srcb = 1;
    while ((1 << srcb) < N) ++srcb;                    // 17 for N=100000

    char* w = (char*)d_ws;
    size_t off = 0;
    auto alloc = [&](size_t bytes) -> void* {
        void* p = w + off;
        off += (bytes + 255) & ~(size_t)255;
        return p;
    };
    int*      row_ptr  = (int*)alloc((size_t)(N + 1) * 4);
    int*      colarr   = (int*)alloc((size_t)E * 4);
    int*      partials = (int*)alloc(256 * 4);
    int*      cursor8  = (int*)alloc(8 * 4);
    float*    dinv     = (float*)alloc((size_t)N * 4);
    unsigned* h1f8     = (unsigned*)alloc((size_t)N * 32 * 4);  // fp8 X@W1 scaled (12.8MB)
    unsigned* h2b      = (unsigned*)alloc((size_t)N * 32 * 4);  // bf16 a1@W2 scaled (12.8MB)
    unsigned* Bp1      = (unsigned*)alloc(4 * 8 * 64 * 16);     // W1 frag stream 32KB
    unsigned* Bp2      = (unsigned*)alloc(4 * 4 * 64 * 16);     // W2 frag stream 16KB
    // pairs (7.5 MB) + cntarr (12.8 MB) alias h1f8+h2b (25.6 MB contiguous);
    // both are dead before k_gemm128_mfma writes h1f8.
    unsigned* pairsU   = (unsigned*)h1f8;
    int*      cntarr   = (int*)((char*)h1f8 + (size_t)NPART * capE * 4);
    (void)ws_size; (void)n_in; (void)out_size;

    int nscan = (N + 1023) / 1024;
    int nbb = (E + EB - 1) / EB;       // 782 bucket blocks
    int ngemm = (N + 63) / 64;

    hipMemsetAsync(cursor8, 0, 8 * 4, stream);
    k_packW2<<<2, 256, 0, stream>>>(W1, Bp1, W2, Bp2);
    k_bucket_ballot<<<nbb, 256, 0, stream>>>(src, dst, cursor8, pairsU,
                                             E, npp, capE, srcb);
    k_count_part<<<NPART * KB, 256, 0, stream>>>(pairsU, cursor8, cntarr,
                                                 npp, capE, srcb);
    k_indeg_scan<<<nscan, 256, 0, stream>>>(cntarr, dinv, row_ptr, partials, N, npp);
    k_scan_partials<<<1, 256, 0, stream>>>(partials, nscan);
    k_finalize_bases<<<(N + 255) / 256, 256, 0, stream>>>(row_ptr, partials, cntarr,
                                                          N, E, npp);
    k_fill2<<<NPART * KB, 256, 0, stream>>>(pairsU, cursor8, cntarr, colarr,
                                            npp, capE, srcb);

    k_gemm128_mfma<<<ngemm, 256, 0, stream>>>(x, Bp1, dinv, (unsigned char*)h1f8, N);
    k_agg_relu_gemm<<<(N + 15) / 16, 256, 0, stream>>>(h1f8, dinv, row_ptr, colarr,
                                                       b1, Bp2, (unsigned short*)h2b, N);
    k_agg_lsm<<<(N + 15) / 16, 256, 0, stream>>>(h2b, dinv, row_ptr, colarr, b2, out, N);
}

// Round 9
// 257.304 us; speedup vs baseline: 1.5725x; 1.0280x over previous
//
#include <hip/hip_runtime.h>
#include <hip/hip_fp16.h>
#include <cstdint>
#include <cstddef>
#include <cstring>

// ---------------- bf16 pack/unpack helpers (RNE) ----------------

__device__ inline unsigned pack_bf16x2(float a, float b) {
    unsigned ua = __float_as_uint(a);
    unsigned ub = __float_as_uint(b);
    ua += 0x7fffu + ((ua >> 16) & 1u);
    ub += 0x7fffu + ((ub >> 16) & 1u);
    return (ua >> 16) | (ub & 0xffff0000u);
}
__device__ inline unsigned short bf16_rne(float v) {
    unsigned u = __float_as_uint(v);
    u += 0x7fffu + ((u >> 16) & 1u);
    return (unsigned short)(u >> 16);
}

// ---------------- fp8 (OCP e4m3fn) pack/unpack ----------------

typedef float fv2 __attribute__((ext_vector_type(2)));

template <bool HI>
__device__ inline fv2 fp8_fv2(unsigned u) {
#if __has_builtin(__builtin_amdgcn_cvt_pk_f32_fp8)
    return __builtin_amdgcn_cvt_pk_f32_fp8((int)u, HI);
#else
    unsigned u2 = HI ? (u >> 16) : (u & 0xffffu);
    unsigned w = (u2 & 0xFFu) | ((u2 & 0xFF00u) << 8);
    unsigned hb = ((w & 0x00800080u) << 8) | ((w & 0x007f007fu) << 7);
    __half2 h2;
    memcpy(&h2, &hb, 4);
    float2 f = __half22float2(h2);
    fv2 r;
    r.x = f.x * 256.0f;
    r.y = f.y * 256.0f;
    return r;
#endif
}

// bf16 pair (packed in a uint) -> fv2  (2 bitops, then packed add on use)
__device__ inline fv2 bfpair(unsigned u) {
    union { unsigned q[2]; fv2 f; } t;
    t.q[0] = u << 16;
    t.q[1] = u & 0xffff0000u;
    return t.f;
}

__device__ inline unsigned f32_to_fp8_byte(float v) {
    unsigned short hb = __half_as_ushort(__float2half(v * 0.00390625f));  // v/256
    unsigned t = hb & 0x7fffu;
    t += 0x3fu + ((t >> 7) & 1u);
    return ((hb >> 8) & 0x80u) | (t >> 7);
}

__device__ inline unsigned char f32_to_fp8_b(float v) {
#if __has_builtin(__builtin_amdgcn_cvt_pk_fp8_f32)
    return (unsigned char)(__builtin_amdgcn_cvt_pk_fp8_f32(v, v, 0, false) & 0xff);
#else
    return (unsigned char)f32_to_fp8_byte(v);
#endif
}

typedef int iv4 __attribute__((ext_vector_type(4)));

#define NPART 8
#define KB    32
#define NPP_MAX 12500
#define EB    2048   // edges per bucket block (8 per thread)
#define COLCAP 1536  // per-block LDS col-index cache (16 nodes, deg avg 16)

// ---------------- CSR build (R6-proven chain) --------
// R7 lesson: mega-fusion pinned all phases at 1 block/CU -> 2x slower. Keep
// the chain; each phase runs at its own occupancy. Boundaries ~1us each.
//  - R3: col scatter-writes confined to L2-sized windows (no amplification)
//  - R5: never issue per-edge global atomics (coherence-point traffic)
//  - R6: ballot bucket -- zero per-edge atomics, 8 global atomics per block

__global__ __launch_bounds__(256) void k_bucket_ballot(const int* __restrict__ src,
                                                       const int* __restrict__ dst,
                                                       int* __restrict__ cursor8,
                                                       unsigned* __restrict__ pairs,
                                                       int E, int npp, int capE,
                                                       int srcb) {
    __shared__ int sWcnt[4][NPART];
    __shared__ int sWoff[4][NPART];
    int tid = threadIdx.x;
    int wv = tid >> 6;
    int lane = tid & 63;
    int base_e = blockIdx.x * EB + tid * 8;
    int nv = min(8, E - base_e);
    if (nv < 0) nv = 0;
    int dv[8], sv[8];
    if (nv == 8) {
        *(iv4*)(dv + 0) = *(const iv4*)(dst + base_e + 0);
        *(iv4*)(dv + 4) = *(const iv4*)(dst + base_e + 4);
        *(iv4*)(sv + 0) = *(const iv4*)(src + base_e + 0);
        *(iv4*)(sv + 4) = *(const iv4*)(src + base_e + 4);
    } else {
        for (int k = 0; k < 8; ++k) {
            dv[k] = (k < nv) ? dst[base_e + k] : -1;
            sv[k] = (k < nv) ? src[base_e + k] : 0;
        }
    }
    unsigned long long below = (1ull << lane) - 1ull;
    int wb[NPART];
#pragma unroll
    for (int pp = 0; pp < NPART; ++pp) wb[pp] = 0;
    int pv[8], pos[8];
#pragma unroll
    for (int s = 0; s < 8; ++s) {
        int d = dv[s];
        int p = (d >= 0) ? (int)((unsigned)d / (unsigned)npp) : NPART;
        pv[s] = p;
        unsigned long long msel = 0;
        int base = 0;
#pragma unroll
        for (int pp = 0; pp < NPART; ++pp) {
            unsigned long long m = __ballot(p == pp);
            if (p == pp) { msel = m; base = wb[pp]; }
            wb[pp] += (int)__popcll(m);   // ballot result is wave-uniform
        }
        pos[s] = base + (int)__popcll(msel & below);
    }
    // wave totals -> LDS (static indexing to keep wb in registers)
    if (lane < NPART) {
        int v = 0;
#pragma unroll
        for (int pp = 0; pp < NPART; ++pp)
            if (lane == pp) v = wb[pp];
        sWcnt[wv][lane] = v;
    }
    __syncthreads();
    if (tid < NPART) {
        int c0 = sWcnt[0][tid], c1 = sWcnt[1][tid], c2 = sWcnt[2][tid], c3 = sWcnt[3][tid];
        int gb = atomicAdd(&cursor8[tid], c0 + c1 + c2 + c3);  // 8 atomics/block
        sWoff[0][tid] = gb;
        sWoff[1][tid] = gb + c0;
        sWoff[2][tid] = gb + c0 + c1;
        sWoff[3][tid] = gb + c0 + c1 + c2;
    }
    __syncthreads();
#pragma unroll
    for (int s = 0; s < 8; ++s) {
        int p = pv[s];
        if (p < NPART) {
            int off = sWoff[wv][p];
            pairs[(size_t)p * capE + off + pos[s]] =
                ((unsigned)(dv[s] - p * npp) << srcb) | (unsigned)sv[s];
        }
    }
}

__global__ __launch_bounds__(256) void k_count_part(const unsigned* __restrict__ pairs,
                                                    const int* __restrict__ cursor8,
                                                    int* __restrict__ cntarr,
                                                    int npp, int capE, int srcb) {
    __shared__ int h[NPP_MAX];
    int p = blockIdx.x & (NPART - 1);
    int b = blockIdx.x >> 3;
    for (int i = threadIdx.x; i < npp; i += 256) h[i] = 0;
    __syncthreads();
    int sz = cursor8[p];
    int chunk = (sz + KB - 1) / KB;
    int s0 = b * chunk;
    int s1 = min(sz, s0 + chunk);
    const unsigned* seg = pairs + (size_t)p * capE;
    for (int i = s0 + threadIdx.x; i < s1; i += 256)
        atomicAdd(&h[seg[i] >> srcb], 1);
    __syncthreads();
    size_t out = (size_t)(p * KB + b) * npp;
    for (int i = threadIdx.x; i < npp; i += 256) cntarr[out + i] = h[i];
}

// Fused: per-node degree (sum of 32 cntarr slices) -> dinv + block-local scan.
__global__ void k_indeg_scan(const int* __restrict__ cntarr,
                             float* __restrict__ dinv,
                             int* __restrict__ row_ptr,
                             int* __restrict__ partials, int n, int npp) {
    __shared__ int s[256];
    int t = threadIdx.x;
    int node0 = blockIdx.x * 1024 + t * 4;
    int v0 = 0, v1 = 0, v2 = 0, v3 = 0;
    if (((npp & 3) == 0) && (node0 + 3 < n) && (node0 / npp == (node0 + 3) / npp)) {
        int p = node0 / npp;
        int dl = node0 - p * npp;
        size_t base = (size_t)p * KB * npp + dl;
        for (int b = 0; b < KB; ++b) {
            iv4 c = *(const iv4*)(cntarr + base + (size_t)b * npp);
            v0 += c.x; v1 += c.y; v2 += c.z; v3 += c.w;
        }
    } else {
        for (int r = 0; r < 4; ++r) {
            int node = node0 + r;
            if (node < n) {
                int p = node / npp;
                int dl = node - p * npp;
                size_t base = (size_t)p * KB * npp + dl;
                int sum = 0;
                for (int b = 0; b < KB; ++b) sum += cntarr[base + (size_t)b * npp];
                if (r == 0) v0 = sum; else if (r == 1) v1 = sum;
                else if (r == 2) v2 = sum; else v3 = sum;
            }
        }
    }
    if (node0 + 0 < n) dinv[node0 + 0] = rsqrtf((float)v0 + 1.0f);
    if (node0 + 1 < n) dinv[node0 + 1] = rsqrtf((float)v1 + 1.0f);
    if (node0 + 2 < n) dinv[node0 + 2] = rsqrtf((float)v2 + 1.0f);
    if (node0 + 3 < n) dinv[node0 + 3] = rsqrtf((float)v3 + 1.0f);
    int sum = v0 + v1 + v2 + v3;
    s[t] = sum;
    __syncthreads();
    for (int off = 1; off < 256; off <<= 1) {
        int x = (t >= off) ? s[t - off] : 0;
        __syncthreads();
        s[t] += x;
        __syncthreads();
    }
    int excl = s[t] - sum;
    if ((node0 + 0) < n) row_ptr[node0 + 0] = excl;
    if ((node0 + 1) < n) row_ptr[node0 + 1] = excl + v0;
    if ((node0 + 2) < n) row_ptr[node0 + 2] = excl + v0 + v1;
    if ((node0 + 3) < n) row_ptr[node0 + 3] = excl + v0 + v1 + v2;
    if (t == 255) partials[blockIdx.x] = s[255];
}

__global__ void k_scan_partials(int* __restrict__ partials, int np) {
    __shared__ int s[256];
    int t = threadIdx.x;
    int v = (t < np) ? partials[t] : 0;
    s[t] = v;
    __syncthreads();
    for (int off = 1; off < 256; off <<= 1) {
        int x = (t >= off) ? s[t - off] : 0;
        __syncthreads();
        s[t] += x;
        __syncthreads();
    }
    if (t < np) partials[t] = s[t] - v;
}

// Fused: row_ptr fixup + per-slice base rewrite (cntarr becomes fill cursors).
__global__ void k_finalize_bases(int* __restrict__ row_ptr,
                                 const int* __restrict__ partials,
                                 int* __restrict__ cntarr, int n, int E, int npp) {
    int i = blockIdx.x * blockDim.x + threadIdx.x;
    if (i >= n) return;
    int rp = row_ptr[i] + partials[i >> 10];
    row_ptr[i] = rp;
    if (i == 0) row_ptr[n] = E;
    int p = (unsigned)i / (unsigned)npp;
    int dl = i - p * npp;
    size_t base = (size_t)p * KB * npp + dl;
    int run = rp;
    for (int b = 0; b < KB; ++b) {
        size_t idx = base + (size_t)b * npp;
        int c = cntarr[idx];
        cntarr[idx] = run;
        run += c;
    }
}

__global__ __launch_bounds__(256) void k_fill2(const unsigned* __restrict__ pairs,
                                               const int* __restrict__ cursor8,
                                               const int* __restrict__ cntarr,
                                               int* __restrict__ col,
                                               int npp, int capE, int srcb) {
    __shared__ int cur[NPP_MAX];
    int p = blockIdx.x & (NPART - 1);
    int b = blockIdx.x >> 3;
    size_t slice = (size_t)(p * KB + b) * npp;
    for (int i = threadIdx.x; i < npp; i += 256) cur[i] = cntarr[slice + i];
    __syncthreads();
    int sz = cursor8[p];
    int chunk = (sz + KB - 1) / KB;
    int s0 = b * chunk;
    int s1 = min(sz, s0 + chunk);
    const unsigned* seg = pairs + (size_t)p * capE;
    unsigned smask = (1u << srcb) - 1u;
    for (int i = s0 + threadIdx.x; i < s1; i += 256) {
        unsigned u = seg[i];
        int pos = atomicAdd(&cur[u >> srcb], 1);
        col[pos] = (int)(u & smask);
    }
}

// ---------------- MFMA GEMMs ----------------
typedef __attribute__((ext_vector_type(8))) short short8;
typedef __attribute__((ext_vector_type(4))) float f32x4;

union FragU {
    short8 s;
    uint4 u4;
    unsigned u[4];
};

__device__ inline void packW_body(const float* __restrict__ W, unsigned* __restrict__ Bp,
                                  int NOUT, int NT) {
    int nf = 4 * NT * 64;
    for (int fid = threadIdx.x; fid < nf; fid += 256) {
        int q = fid / (NT * 64);
        int rem = fid - q * NT * 64;
        int nt = rem >> 6;
        int lane = rem & 63;
        int k0 = q * 32 + (lane >> 4) * 8;
        int ncol = nt * 16 + (lane & 15);
        unsigned u[4];
        for (int h = 0; h < 4; ++h) {
            float a = W[(k0 + 2 * h) * NOUT + ncol];
            float b = W[(k0 + 2 * h + 1) * NOUT + ncol];
            u[h] = pack_bf16x2(a, b);
        }
        uint4 o = {u[0], u[1], u[2], u[3]};
        *(uint4*)(Bp + (size_t)fid * 4) = o;
    }
}

// both weight packs in one dispatch (block 0 -> W1, block 1 -> W2)
__global__ void k_packW2(const float* __restrict__ W1, unsigned* __restrict__ Bp1,
                         const float* __restrict__ W2, unsigned* __restrict__ Bp2) {
    if (blockIdx.x == 0) packW_body(W1, Bp1, 128, 8);
    else                 packW_body(W2, Bp2, 64, 4);
}

__global__ __launch_bounds__(256) void k_gemm128_mfma(const float* __restrict__ X,
                                                      const unsigned* __restrict__ Bp,
                                                      const float* __restrict__ dinv,
                                                      unsigned char* __restrict__ H8,
                                                      int n) {
    int w = threadIdx.x >> 6;
    int lane = threadIdx.x & 63;
    int quad = lane >> 4;
    int lrow = lane & 15;
    int row0 = blockIdx.x * 64 + w * 16;
    int rowA = min(row0 + lrow, n - 1);

    f32x4 acc[8];
    for (int nt = 0; nt < 8; ++nt) acc[nt] = (f32x4){0.f, 0.f, 0.f, 0.f};

    for (int q = 0; q < 4; ++q) {
        const float* xp = X + (size_t)rowA * 128 + q * 32 + quad * 8;
        float4 x0 = *(const float4*)xp;
        float4 x1 = *(const float4*)(xp + 4);
        FragU a;
        a.u[0] = pack_bf16x2(x0.x, x0.y);
        a.u[1] = pack_bf16x2(x0.z, x0.w);
        a.u[2] = pack_bf16x2(x1.x, x1.y);
        a.u[3] = pack_bf16x2(x1.z, x1.w);
        for (int nt = 0; nt < 8; ++nt) {
            FragU b;
            b.u4 = *(const uint4*)(Bp + ((size_t)(q * 8 + nt) * 64 + lane) * 4);
            acc[nt] = __builtin_amdgcn_mfma_f32_16x16x32_bf16(a.s, b.s, acc[nt], 0, 0, 0);
        }
    }

    int rbase = row0 + quad * 4;
    float dv[4];
    if (rbase + 3 < n) {
        float4 d4 = *(const float4*)(dinv + rbase);
        dv[0] = d4.x; dv[1] = d4.y; dv[2] = d4.z; dv[3] = d4.w;
    } else {
        for (int r = 0; r < 4; ++r) dv[r] = dinv[min(rbase + r, n - 1)];
    }
    for (int nt = 0; nt < 8; ++nt) {
        for (int r = 0; r < 4; ++r) {
            int row = rbase + r;
            if (row < n)
                H8[(size_t)row * 128 + nt * 16 + lrow] = f32_to_fp8_b(dv[r] * acc[nt][r]);
        }
    }
}

// ---------------- Layer-1 aggregation FUSED with the W2 GEMM ----------------
// R13-proven agg structure (quarter-wave per node). R9: the block's 16 nodes
// are consecutive, so their CSR col entries are ONE contiguous range --
// stage it into LDS once (coalesced), then the gather loop reads indices via
// LDS broadcast instead of a serialized global round-trip per 8-edge batch.
// Quarter-uniform fallback to global col for pathological blocks (>COLCAP).
#define ACC8(u) \
    a0 += fp8_fv2<false>((u).x); a1 += fp8_fv2<true>((u).x); \
    a2 += fp8_fv2<false>((u).y); a3 += fp8_fv2<true>((u).y);

__global__ __launch_bounds__(256) void k_agg_relu_gemm(const unsigned* __restrict__ hs,
                                                       const float* __restrict__ dinv,
                                                       const int* __restrict__ row_ptr,
                                                       const int* __restrict__ col,
                                                       const float* __restrict__ bias,
                                                       const unsigned* __restrict__ Bp2,
                                                       unsigned short* __restrict__ H16,
                                                       int n) {
    __shared__ unsigned s_a[16][68];
    __shared__ int s_rp[17];
    __shared__ int s_col[COLCAP];
    int tid = threadIdx.x;
    int q16 = tid >> 4;                 // local node 0..15
    int node0 = blockIdx.x * 16;
    int node = node0 + q16;
    int l = tid & 15;
    bool alive = node < n;
    int nodeC = alive ? node : (n - 1);
    if (tid < 17) s_rp[tid] = row_ptr[min(node0 + tid, n)];
    __syncthreads();
    int base = s_rp[0];
    int total = s_rp[16] - base;
    int nld = min(total, COLCAP);
    for (int i = tid; i < nld; i += 256) s_col[i] = col[base + i];
    __syncthreads();

    const uint2* hrow = (const uint2*)hs;
    fv2 a0 = {0.f, 0.f}, a1 = {0.f, 0.f}, a2 = {0.f, 0.f}, a3 = {0.f, 0.f};
    if (alive) {   // self term
        uint2 u = hrow[(size_t)node * 16 + l];
        ACC8(u)
    }
    int kk = s_rp[q16] - base;
    int kend = s_rp[q16 + 1] - base;
    if (kend <= COLCAP) {   // fast path: indices from LDS (broadcast reads)
        for (; kk + 8 <= kend; kk += 8) {
            int cA = s_col[kk + 0], cB = s_col[kk + 1], cC = s_col[kk + 2], cD = s_col[kk + 3];
            int cE = s_col[kk + 4], cF = s_col[kk + 5], cG = s_col[kk + 6], cH = s_col[kk + 7];
            uint2 uA = hrow[(size_t)cA * 16 + l];
            uint2 uB = hrow[(size_t)cB * 16 + l];
            uint2 uC = hrow[(size_t)cC * 16 + l];
            uint2 uD = hrow[(size_t)cD * 16 + l];
            uint2 uE = hrow[(size_t)cE * 16 + l];
            uint2 uF = hrow[(size_t)cF * 16 + l];
            uint2 uG = hrow[(size_t)cG * 16 + l];
            uint2 uH = hrow[(size_t)cH * 16 + l];
            ACC8(uA) ACC8(uB) ACC8(uC) ACC8(uD)
            ACC8(uE) ACC8(uF) ACC8(uG) ACC8(uH)
        }
        for (; kk + 4 <= kend; kk += 4) {
            int cA = s_col[kk + 0], cB = s_col[kk + 1], cC = s_col[kk + 2], cD = s_col[kk + 3];
            uint2 uA = hrow[(size_t)cA * 16 + l];
            uint2 uB = hrow[(size_t)cB * 16 + l];
            uint2 uC = hrow[(size_t)cC * 16 + l];
            uint2 uD = hrow[(size_t)cD * 16 + l];
            ACC8(uA) ACC8(uB) ACC8(uC) ACC8(uD)
        }
        for (; kk < kend; ++kk) {
            uint2 u = hrow[(size_t)s_col[kk] * 16 + l];
            ACC8(u)
        }
    } else {                 // rare fallback: global col
        const int* cp = col + base;
        for (; kk + 4 <= kend; kk += 4) {
            int cA = cp[kk + 0], cB = cp[kk + 1], cC = cp[kk + 2], cD = cp[kk + 3];
            uint2 uA = hrow[(size_t)cA * 16 + l];
            uint2 uB = hrow[(size_t)cB * 16 + l];
            uint2 uC = hrow[(size_t)cC * 16 + l];
            uint2 uD = hrow[(size_t)cD * 16 + l];
            ACC8(uA) ACC8(uB) ACC8(uC) ACC8(uD)
        }
        for (; kk < kend; ++kk) {
            uint2 u = hrow[(size_t)cp[kk] * 16 + l];
            ACC8(u)
        }
    }
    // epilogue: every lane finalizes its own 8 columns -> bf16 into LDS tile
    {
        float di = dinv[nodeC];
        float4 b4a = *(const float4*)(bias + 8 * l);
        float4 b4b = *(const float4*)(bias + 8 * l + 4);
        float v0 = fmaf(di, a0.x, b4a.x);
        float v1 = fmaf(di, a0.y, b4a.y);
        float v2 = fmaf(di, a1.x, b4a.z);
        float v3 = fmaf(di, a1.y, b4a.w);
        float v4 = fmaf(di, a2.x, b4b.x);
        float v5 = fmaf(di, a2.y, b4b.y);
        float v6 = fmaf(di, a3.x, b4b.z);
        float v7 = fmaf(di, a3.y, b4b.w);
        v0 = v0 > 0.f ? v0 : 0.f;
        v1 = v1 > 0.f ? v1 : 0.f;
        v2 = v2 > 0.f ? v2 : 0.f;
        v3 = v3 > 0.f ? v3 : 0.f;
        v4 = v4 > 0.f ? v4 : 0.f;
        v5 = v5 > 0.f ? v5 : 0.f;
        v6 = v6 > 0.f ? v6 : 0.f;
        v7 = v7 > 0.f ? v7 : 0.f;
        uint4 o = {pack_bf16x2(v0, v1), pack_bf16x2(v2, v3),
                   pack_bf16x2(v4, v5), pack_bf16x2(v6, v7)};
        *(uint4*)&s_a[q16][4 * l] = o;
    }
    __syncthreads();
    // W2 GEMM: 16 nodes x 128 @ 128 x 64. Wave w owns N-tile nt=w (16 cols).
    // Fragment layouts identical to the standalone gemm64 (A: row=lane&15,
    // k-chunk=q*16+4*quad uints; C: row=quad*4+r, col=nt*16+(lane&15)).
    {
        int lane = threadIdx.x & 63;
        int w = threadIdx.x >> 6;
        int quad = lane >> 4;
        int lrow = lane & 15;
        f32x4 acc = (f32x4){0.f, 0.f, 0.f, 0.f};
        for (int q = 0; q < 4; ++q) {
            FragU a, b;
            a.u4 = *(const uint4*)&s_a[lrow][16 * q + 4 * quad];
            b.u4 = *(const uint4*)(Bp2 + ((size_t)(q * 4 + w) * 64 + lane) * 4);
            acc = __builtin_amdgcn_mfma_f32_16x16x32_bf16(a.s, b.s, acc, 0, 0, 0);
        }
        int rbase = blockIdx.x * 16 + quad * 4;
        for (int r = 0; r < 4; ++r) {
            int nd = rbase + r;
            if (nd < n)
                H16[(size_t)nd * 64 + w * 16 + lrow] = bf16_rne(dinv[nd] * acc[r]);
        }
    }
}

// Layer 2: hs rows = 16 uint2 (64 bf16). Lane owns bf16 cols 4l..4l+3.
// Same LDS col-index staging; fused log_softmax (16-lane quarter reduce).
#define ACCL(u) \
    aX += bfpair((u).x); aY += bfpair((u).y);

__global__ __launch_bounds__(256) void k_agg_lsm(const unsigned* __restrict__ hs,
                                                 const float* __restrict__ dinv,
                                                 const int* __restrict__ row_ptr,
                                                 const int* __restrict__ col,
                                                 const float* __restrict__ bias,
                                                 float* __restrict__ out, int n) {
    __shared__ int s_rp[17];
    __shared__ int s_col[COLCAP];
    int tid = threadIdx.x;
    int q16 = tid >> 4;
    int node0 = blockIdx.x * 16;
    int node = node0 + q16;
    int l = tid & 15;
    bool alive = node < n;
    int nodeC = alive ? node : (n - 1);
    if (tid < 17) s_rp[tid] = row_ptr[min(node0 + tid, n)];
    __syncthreads();
    int base = s_rp[0];
    int total = s_rp[16] - base;
    int nld = min(total, COLCAP);
    for (int i = tid; i < nld; i += 256) s_col[i] = col[base + i];
    __syncthreads();

    const uint2* hrow = (const uint2*)hs;
    fv2 aX = {0.f, 0.f}, aY = {0.f, 0.f};
    if (alive) {   // self term
        uint2 u = hrow[(size_t)node * 16 + l];
        ACCL(u)
    }
    int kk = s_rp[q16] - base;
    int kend = s_rp[q16 + 1] - base;
    if (kend <= COLCAP) {
        for (; kk + 8 <= kend; kk += 8) {
            int cA = s_col[kk + 0], cB = s_col[kk + 1], cC = s_col[kk + 2], cD = s_col[kk + 3];
            int cE = s_col[kk + 4], cF = s_col[kk + 5], cG = s_col[kk + 6], cH = s_col[kk + 7];
            uint2 uA = hrow[(size_t)cA * 16 + l];
            uint2 uB = hrow[(size_t)cB * 16 + l];
            uint2 uC = hrow[(size_t)cC * 16 + l];
            uint2 uD = hrow[(size_t)cD * 16 + l];
            uint2 uE = hrow[(size_t)cE * 16 + l];
            uint2 uF = hrow[(size_t)cF * 16 + l];
            uint2 uG = hrow[(size_t)cG * 16 + l];
            uint2 uH = hrow[(size_t)cH * 16 + l];
            ACCL(uA) ACCL(uB) ACCL(uC) ACCL(uD)
            ACCL(uE) ACCL(uF) ACCL(uG) ACCL(uH)
        }
        for (; kk + 4 <= kend; kk += 4) {
            int cA = s_col[kk + 0], cB = s_col[kk + 1], cC = s_col[kk + 2], cD = s_col[kk + 3];
            uint2 uA = hrow[(size_t)cA * 16 + l];
            uint2 uB = hrow[(size_t)cB * 16 + l];
            uint2 uC = hrow[(size_t)cC * 16 + l];
            uint2 uD = hrow[(size_t)cD * 16 + l];
            ACCL(uA) ACCL(uB) ACCL(uC) ACCL(uD)
        }
        for (; kk < kend; ++kk) {
            uint2 u = hrow[(size_t)s_col[kk] * 16 + l];
            ACCL(u)
        }
    } else {
        const int* cp = col + base;
        for (; kk + 4 <= kend; kk += 4) {
            int cA = cp[kk + 0], cB = cp[kk + 1], cC = cp[kk + 2], cD = cp[kk + 3];
            uint2 uA = hrow[(size_t)cA * 16 + l];
            uint2 uB = hrow[(size_t)cB * 16 + l];
            uint2 uC = hrow[(size_t)cC * 16 + l];
            uint2 uD = hrow[(size_t)cD * 16 + l];
            ACCL(uA) ACCL(uB) ACCL(uC) ACCL(uD)
        }
        for (; kk < kend; ++kk) {
            uint2 u = hrow[(size_t)cp[kk] * 16 + l];
            ACCL(u)
        }
    }
    float di = dinv[nodeC];
    float4 b4 = *(const float4*)(bias + 4 * l);
    float v0 = fmaf(di, aX.x, b4.x);
    float v1 = fmaf(di, aX.y, b4.y);
    float v2 = fmaf(di, aY.x, b4.z);
    float v3 = fmaf(di, aY.y, b4.w);
    float m = fmaxf(fmaxf(v0, v1), fmaxf(v2, v3));
    for (int off = 8; off; off >>= 1) m = fmaxf(m, __shfl_xor(m, off));
    float s = __expf(v0 - m) + __expf(v1 - m) + __expf(v2 - m) + __expf(v3 - m);
    for (int off = 8; off; off >>= 1) s += __shfl_xor(s, off);
    float ls = __logf(s);
    if (alive) {
        float4 o = {v0 - m - ls, v1 - m - ls, v2 - m - ls, v3 - m - ls};
        *(float4*)(out + (size_t)node * 64 + 4 * l) = o;
    }
}

// ---------------- launcher ----------------

extern "C" void kernel_launch(void* const* d_in, const int* in_sizes, int n_in,
                              void* d_out, int out_size, void* d_ws, size_t ws_size,
                              hipStream_t stream) {
    const float* x  = (const float*)d_in[0];
    const int*   ei = (const int*)d_in[1];
    const float* W1 = (const float*)d_in[2];
    const float* b1 = (const float*)d_in[3];
    const float* W2 = (const float*)d_in[4];
    const float* b2 = (const float*)d_in[5];
    float* out = (float*)d_out;

    const int N = in_sizes[0] / 128;   // 100000
    const int E = in_sizes[1] / 2;     // 1600000
    const int* src = ei;
    const int* dst = ei + E;
    const int npp = (N + NPART - 1) / NPART;           // 12500
    const int capE = (E + NPART - 1) / NPART + 32768;  // segment capacity + slack
    int srcb = 1;
    while ((1 << srcb) < N) ++srcb;                    // 17 for N=100000

    char* w = (char*)d_ws;
    size_t off = 0;
    auto alloc = [&](size_t bytes) -> void* {
        void* p = w + off;
        off += (bytes + 255) & ~(size_t)255;
        return p;
    };
    int*      row_ptr  = (int*)alloc((size_t)(N + 1) * 4);
    int*      colarr   = (int*)alloc((size_t)E * 4);
    int*      partials = (int*)alloc(256 * 4);
    int*      cursor8  = (int*)alloc(8 * 4);
    float*    dinv     = (float*)alloc((size_t)N * 4);
    unsigned* h1f8     = (unsigned*)alloc((size_t)N * 32 * 4);  // fp8 X@W1 scaled (12.8MB)
    unsigned* h2b      = (unsigned*)alloc((size_t)N * 32 * 4);  // bf16 a1@W2 scaled (12.8MB)
    unsigned* Bp1      = (unsigned*)alloc(4 * 8 * 64 * 16);     // W1 frag stream 32KB
    unsigned* Bp2      = (unsigned*)alloc(4 * 4 * 64 * 16);     // W2 frag stream 16KB
    // pairs (7.5 MB) + cntarr (12.8 MB) alias h1f8+h2b (25.6 MB contiguous);
    // both are dead before k_gemm128_mfma writes h1f8.
    unsigned* pairsU   = (unsigned*)h1f8;
    int*      cntarr   = (int*)((char*)h1f8 + (size_t)NPART * capE * 4);
    (void)ws_size; (void)n_in; (void)out_size;

    int nscan = (N + 1023) / 1024;
    int nbb = (E + EB - 1) / EB;       // 782 bucket blocks
    int ngemm = (N + 63) / 64;

    hipMemsetAsync(cursor8, 0, 8 * 4, stream);
    k_packW2<<<2, 256, 0, stream>>>(W1, Bp1, W2, Bp2);
    k_bucket_ballot<<<nbb, 256, 0, stream>>>(src, dst, cursor8, pairsU,
                                             E, npp, capE, srcb);
    k_count_part<<<NPART * KB, 256, 0, stream>>>(pairsU, cursor8, cntarr,
                                                 npp, capE, srcb);
    k_indeg_scan<<<nscan, 256, 0, stream>>>(cntarr, dinv, row_ptr, partials, N, npp);
    k_scan_partials<<<1, 256, 0, stream>>>(partials, nscan);
    k_finalize_bases<<<(N + 255) / 256, 256, 0, stream>>>(row_ptr, partials, cntarr,
                                                          N, E, npp);
    k_fill2<<<NPART * KB, 256, 0, stream>>>(pairsU, cursor8, cntarr, colarr,
                                            npp, capE, srcb);

    k_gemm128_mfma<<<ngemm, 256, 0, stream>>>(x, Bp1, dinv, (unsigned char*)h1f8, N);
    k_agg_relu_gemm<<<(N + 15) / 16, 256, 0, stream>>>(h1f8, dinv, row_ptr, colarr,
                                                       b1, Bp2, (unsigned short*)h2b, N);
    k_agg_lsm<<<(N + 15) / 16, 256, 0, stream>>>(h2b, dinv, row_ptr, colarr, b2, out, N);
}

// Round 10
// 250.766 us; speedup vs baseline: 1.6135x; 1.0261x over previous
//
#include <hip/hip_runtime.h>
#include <hip/hip_fp16.h>
#include <cstdint>
#include <cstddef>
#include <cstring>

// ---------------- bf16 pack/unpack helpers (RNE) ----------------

__device__ inline unsigned pack_bf16x2(float a, float b) {
    unsigned ua = __float_as_uint(a);
    unsigned ub = __float_as_uint(b);
    ua += 0x7fffu + ((ua >> 16) & 1u);
    ub += 0x7fffu + ((ub >> 16) & 1u);
    return (ua >> 16) | (ub & 0xffff0000u);
}
__device__ inline unsigned short bf16_rne(float v) {
    unsigned u = __float_as_uint(v);
    u += 0x7fffu + ((u >> 16) & 1u);
    return (unsigned short)(u >> 16);
}

// ---------------- fp8 (OCP e4m3fn) pack/unpack ----------------

typedef float fv2 __attribute__((ext_vector_type(2)));

template <bool HI>
__device__ inline fv2 fp8_fv2(unsigned u) {
#if __has_builtin(__builtin_amdgcn_cvt_pk_f32_fp8)
    return __builtin_amdgcn_cvt_pk_f32_fp8((int)u, HI);
#else
    unsigned u2 = HI ? (u >> 16) : (u & 0xffffu);
    unsigned w = (u2 & 0xFFu) | ((u2 & 0xFF00u) << 8);
    unsigned hb = ((w & 0x00800080u) << 8) | ((w & 0x007f007fu) << 7);
    __half2 h2;
    memcpy(&h2, &hb, 4);
    float2 f = __half22float2(h2);
    fv2 r;
    r.x = f.x * 256.0f;
    r.y = f.y * 256.0f;
    return r;
#endif
}

// bf16 pair (packed in a uint) -> fv2  (2 bitops, then packed add on use)
__device__ inline fv2 bfpair(unsigned u) {
    union { unsigned q[2]; fv2 f; } t;
    t.q[0] = u << 16;
    t.q[1] = u & 0xffff0000u;
    return t.f;
}

__device__ inline unsigned f32_to_fp8_byte(float v) {
    unsigned short hb = __half_as_ushort(__float2half(v * 0.00390625f));  // v/256
    unsigned t = hb & 0x7fffu;
    t += 0x3fu + ((t >> 7) & 1u);
    return ((hb >> 8) & 0x80u) | (t >> 7);
}

__device__ inline unsigned char f32_to_fp8_b(float v) {
#if __has_builtin(__builtin_amdgcn_cvt_pk_fp8_f32)
    return (unsigned char)(__builtin_amdgcn_cvt_pk_fp8_f32(v, v, 0, false) & 0xff);
#else
    return (unsigned char)f32_to_fp8_byte(v);
#endif
}

typedef int iv4 __attribute__((ext_vector_type(4)));

#define NPART 8
#define KB    32
#define NPP_MAX 12500
#define EB    2048   // edges per bucket block (8 per thread)
#define COLCAP 1536  // per-block LDS col-index cache (16 nodes, deg avg 16)

// ---------------- CSR build (R6-proven chain) --------
// R7 lesson: mega-fusion pinned all phases at 1 block/CU -> 2x slower. Keep
// the chain; each phase runs at its own occupancy. Boundaries ~1us each.
//  - R3: col scatter-writes confined to L2-sized windows (no amplification)
//  - R5: never issue per-edge global atomics (coherence-point traffic)
//  - R6: ballot bucket -- zero per-edge atomics, 8 global atomics per block
// R10: finalize_bases preloads its 32 slice counts into registers (the
// interleaved read-modify-write over the same array falsely serialized the
// loads); scan_partials folded into finalize (R7 phase-3 redundant-scan
// pattern); cursor8/partials zeroing folded into packW2.

__global__ __launch_bounds__(256) void k_bucket_ballot(const int* __restrict__ src,
                                                       const int* __restrict__ dst,
                                                       int* __restrict__ cursor8,
                                                       unsigned* __restrict__ pairs,
                                                       int E, int npp, int capE,
                                                       int srcb) {
    __shared__ int sWcnt[4][NPART];
    __shared__ int sWoff[4][NPART];
    int tid = threadIdx.x;
    int wv = tid >> 6;
    int lane = tid & 63;
    int base_e = blockIdx.x * EB + tid * 8;
    int nv = min(8, E - base_e);
    if (nv < 0) nv = 0;
    int dv[8], sv[8];
    if (nv == 8) {
        *(iv4*)(dv + 0) = *(const iv4*)(dst + base_e + 0);
        *(iv4*)(dv + 4) = *(const iv4*)(dst + base_e + 4);
        *(iv4*)(sv + 0) = *(const iv4*)(src + base_e + 0);
        *(iv4*)(sv + 4) = *(const iv4*)(src + base_e + 4);
    } else {
        for (int k = 0; k < 8; ++k) {
            dv[k] = (k < nv) ? dst[base_e + k] : -1;
            sv[k] = (k < nv) ? src[base_e + k] : 0;
        }
    }
    unsigned long long below = (1ull << lane) - 1ull;
    int wb[NPART];
#pragma unroll
    for (int pp = 0; pp < NPART; ++pp) wb[pp] = 0;
    int pv[8], pos[8];
#pragma unroll
    for (int s = 0; s < 8; ++s) {
        int d = dv[s];
        int p = (d >= 0) ? (int)((unsigned)d / (unsigned)npp) : NPART;
        pv[s] = p;
        unsigned long long msel = 0;
        int base = 0;
#pragma unroll
        for (int pp = 0; pp < NPART; ++pp) {
            unsigned long long m = __ballot(p == pp);
            if (p == pp) { msel = m; base = wb[pp]; }
            wb[pp] += (int)__popcll(m);   // ballot result is wave-uniform
        }
        pos[s] = base + (int)__popcll(msel & below);
    }
    // wave totals -> LDS (static indexing to keep wb in registers)
    if (lane < NPART) {
        int v = 0;
#pragma unroll
        for (int pp = 0; pp < NPART; ++pp)
            if (lane == pp) v = wb[pp];
        sWcnt[wv][lane] = v;
    }
    __syncthreads();
    if (tid < NPART) {
        int c0 = sWcnt[0][tid], c1 = sWcnt[1][tid], c2 = sWcnt[2][tid], c3 = sWcnt[3][tid];
        int gb = atomicAdd(&cursor8[tid], c0 + c1 + c2 + c3);  // 8 atomics/block
        sWoff[0][tid] = gb;
        sWoff[1][tid] = gb + c0;
        sWoff[2][tid] = gb + c0 + c1;
        sWoff[3][tid] = gb + c0 + c1 + c2;
    }
    __syncthreads();
#pragma unroll
    for (int s = 0; s < 8; ++s) {
        int p = pv[s];
        if (p < NPART) {
            int off = sWoff[wv][p];
            pairs[(size_t)p * capE + off + pos[s]] =
                ((unsigned)(dv[s] - p * npp) << srcb) | (unsigned)sv[s];
        }
    }
}

__global__ __launch_bounds__(256) void k_count_part(const unsigned* __restrict__ pairs,
                                                    const int* __restrict__ cursor8,
                                                    int* __restrict__ cntarr,
                                                    int npp, int capE, int srcb) {
    __shared__ int h[NPP_MAX];
    int p = blockIdx.x & (NPART - 1);
    int b = blockIdx.x >> 3;
    for (int i = threadIdx.x; i < npp; i += 256) h[i] = 0;
    __syncthreads();
    int sz = cursor8[p];
    int chunk = (sz + KB - 1) / KB;
    int s0 = b * chunk;
    int s1 = min(sz, s0 + chunk);
    const unsigned* seg = pairs + (size_t)p * capE;
    for (int i = s0 + threadIdx.x; i < s1; i += 256)
        atomicAdd(&h[seg[i] >> srcb], 1);
    __syncthreads();
    size_t out = (size_t)(p * KB + b) * npp;
    for (int i = threadIdx.x; i < npp; i += 256) cntarr[out + i] = h[i];
}

// Fused: per-node degree (sum of 32 cntarr slices) -> dinv + block-local scan.
__global__ void k_indeg_scan(const int* __restrict__ cntarr,
                             float* __restrict__ dinv,
                             int* __restrict__ row_ptr,
                             int* __restrict__ partials, int n, int npp) {
    __shared__ int s[256];
    int t = threadIdx.x;
    int node0 = blockIdx.x * 1024 + t * 4;
    int v0 = 0, v1 = 0, v2 = 0, v3 = 0;
    if (((npp & 3) == 0) && (node0 + 3 < n) && (node0 / npp == (node0 + 3) / npp)) {
        int p = node0 / npp;
        int dl = node0 - p * npp;
        size_t base = (size_t)p * KB * npp + dl;
        for (int b = 0; b < KB; ++b) {
            iv4 c = *(const iv4*)(cntarr + base + (size_t)b * npp);
            v0 += c.x; v1 += c.y; v2 += c.z; v3 += c.w;
        }
    } else {
        for (int r = 0; r < 4; ++r) {
            int node = node0 + r;
            if (node < n) {
                int p = node / npp;
                int dl = node - p * npp;
                size_t base = (size_t)p * KB * npp + dl;
                int sum = 0;
                for (int b = 0; b < KB; ++b) sum += cntarr[base + (size_t)b * npp];
                if (r == 0) v0 = sum; else if (r == 1) v1 = sum;
                else if (r == 2) v2 = sum; else v3 = sum;
            }
        }
    }
    if (node0 + 0 < n) dinv[node0 + 0] = rsqrtf((float)v0 + 1.0f);
    if (node0 + 1 < n) dinv[node0 + 1] = rsqrtf((float)v1 + 1.0f);
    if (node0 + 2 < n) dinv[node0 + 2] = rsqrtf((float)v2 + 1.0f);
    if (node0 + 3 < n) dinv[node0 + 3] = rsqrtf((float)v3 + 1.0f);
    int sum = v0 + v1 + v2 + v3;
    s[t] = sum;
    __syncthreads();
    for (int off = 1; off < 256; off <<= 1) {
        int x = (t >= off) ? s[t - off] : 0;
        __syncthreads();
        s[t] += x;
        __syncthreads();
    }
    int excl = s[t] - sum;
    if ((node0 + 0) < n) row_ptr[node0 + 0] = excl;
    if ((node0 + 1) < n) row_ptr[node0 + 1] = excl + v0;
    if ((node0 + 2) < n) row_ptr[node0 + 2] = excl + v0 + v1;
    if ((node0 + 3) < n) row_ptr[node0 + 3] = excl + v0 + v1 + v2;
    if (t == 255) partials[blockIdx.x] = s[255];
}

// Fused (R10): redundant in-block scan of partials (R7 phase-3 pattern) +
// row_ptr fixup + per-slice base rewrite with REGISTER-PRELOADED counts.
// The old interleaved read/write over cntarr serialized 32 global loads per
// thread (compiler can't prove no-alias); preloading batches all 32 loads.
__global__ void k_finalize_bases(int* __restrict__ row_ptr,
                                 const int* __restrict__ partials,
                                 int* __restrict__ cntarr, int n, int E, int npp) {
    __shared__ int s[256];
    int t = threadIdx.x;
    {   // redundant exclusive scan of partials[0..255] (zero-padded past nscan)
        int v = partials[t];
        s[t] = v;
        __syncthreads();
        for (int off = 1; off < 256; off <<= 1) {
            int x = (t >= off) ? s[t - off] : 0;
            __syncthreads();
            s[t] += x;
            __syncthreads();
        }
        int excl = s[t] - v;
        __syncthreads();
        s[t] = excl;
        __syncthreads();
    }
    int i = blockIdx.x * 256 + t;
    if (i >= n) return;
    int rp = row_ptr[i] + s[i >> 10];
    row_ptr[i] = rp;
    if (i == 0) row_ptr[n] = E;
    int p = (unsigned)i / (unsigned)npp;
    int dl = i - p * npp;
    size_t base = (size_t)p * KB * npp + dl;
    int c[KB];
#pragma unroll
    for (int b = 0; b < KB; ++b) c[b] = cntarr[base + (size_t)b * npp];
    int run = rp;
#pragma unroll
    for (int b = 0; b < KB; ++b) {
        cntarr[base + (size_t)b * npp] = run;
        run += c[b];
    }
}

__global__ __launch_bounds__(256) void k_fill2(const unsigned* __restrict__ pairs,
                                               const int* __restrict__ cursor8,
                                               const int* __restrict__ cntarr,
                                               int* __restrict__ col,
                                               int npp, int capE, int srcb) {
    __shared__ int cur[NPP_MAX];
    int p = blockIdx.x & (NPART - 1);
    int b = blockIdx.x >> 3;
    size_t slice = (size_t)(p * KB + b) * npp;
    for (int i = threadIdx.x; i < npp; i += 256) cur[i] = cntarr[slice + i];
    __syncthreads();
    int sz = cursor8[p];
    int chunk = (sz + KB - 1) / KB;
    int s0 = b * chunk;
    int s1 = min(sz, s0 + chunk);
    const unsigned* seg = pairs + (size_t)p * capE;
    unsigned smask = (1u << srcb) - 1u;
    for (int i = s0 + threadIdx.x; i < s1; i += 256) {
        unsigned u = seg[i];
        int pos = atomicAdd(&cur[u >> srcb], 1);
        col[pos] = (int)(u & smask);
    }
}

// ---------------- MFMA GEMMs ----------------
typedef __attribute__((ext_vector_type(8))) short short8;
typedef __attribute__((ext_vector_type(4))) float f32x4;

union FragU {
    short8 s;
    uint4 u4;
    unsigned u[4];
};

__device__ inline void packW_body(const float* __restrict__ W, unsigned* __restrict__ Bp,
                                  int NOUT, int NT) {
    int nf = 4 * NT * 64;
    for (int fid = threadIdx.x; fid < nf; fid += 256) {
        int q = fid / (NT * 64);
        int rem = fid - q * NT * 64;
        int nt = rem >> 6;
        int lane = rem & 63;
        int k0 = q * 32 + (lane >> 4) * 8;
        int ncol = nt * 16 + (lane & 15);
        unsigned u[4];
        for (int h = 0; h < 4; ++h) {
            float a = W[(k0 + 2 * h) * NOUT + ncol];
            float b = W[(k0 + 2 * h + 1) * NOUT + ncol];
            u[h] = pack_bf16x2(a, b);
        }
        uint4 o = {u[0], u[1], u[2], u[3]};
        *(uint4*)(Bp + (size_t)fid * 4) = o;
    }
}

// both weight packs in one dispatch; block 0 also zeroes cursor8 + partials
__global__ void k_packW2(const float* __restrict__ W1, unsigned* __restrict__ Bp1,
                         const float* __restrict__ W2, unsigned* __restrict__ Bp2,
                         int* __restrict__ cursor8, int* __restrict__ partials) {
    if (blockIdx.x == 0) {
        if (threadIdx.x < 8) cursor8[threadIdx.x] = 0;
        partials[threadIdx.x] = 0;
        packW_body(W1, Bp1, 128, 8);
    } else {
        packW_body(W2, Bp2, 64, 4);
    }
}

__global__ __launch_bounds__(256) void k_gemm128_mfma(const float* __restrict__ X,
                                                      const unsigned* __restrict__ Bp,
                                                      const float* __restrict__ dinv,
                                                      unsigned char* __restrict__ H8,
                                                      int n) {
    int w = threadIdx.x >> 6;
    int lane = threadIdx.x & 63;
    int quad = lane >> 4;
    int lrow = lane & 15;
    int row0 = blockIdx.x * 64 + w * 16;
    int rowA = min(row0 + lrow, n - 1);

    f32x4 acc[8];
    for (int nt = 0; nt < 8; ++nt) acc[nt] = (f32x4){0.f, 0.f, 0.f, 0.f};

    for (int q = 0; q < 4; ++q) {
        const float* xp = X + (size_t)rowA * 128 + q * 32 + quad * 8;
        float4 x0 = *(const float4*)xp;
        float4 x1 = *(const float4*)(xp + 4);
        FragU a;
        a.u[0] = pack_bf16x2(x0.x, x0.y);
        a.u[1] = pack_bf16x2(x0.z, x0.w);
        a.u[2] = pack_bf16x2(x1.x, x1.y);
        a.u[3] = pack_bf16x2(x1.z, x1.w);
        for (int nt = 0; nt < 8; ++nt) {
            FragU b;
            b.u4 = *(const uint4*)(Bp + ((size_t)(q * 8 + nt) * 64 + lane) * 4);
            acc[nt] = __builtin_amdgcn_mfma_f32_16x16x32_bf16(a.s, b.s, acc[nt], 0, 0, 0);
        }
    }

    int rbase = row0 + quad * 4;
    float dv[4];
    if (rbase + 3 < n) {
        float4 d4 = *(const float4*)(dinv + rbase);
        dv[0] = d4.x; dv[1] = d4.y; dv[2] = d4.z; dv[3] = d4.w;
    } else {
        for (int r = 0; r < 4; ++r) dv[r] = dinv[min(rbase + r, n - 1)];
    }
    for (int nt = 0; nt < 8; ++nt) {
        for (int r = 0; r < 4; ++r) {
            int row = rbase + r;
            if (row < n)
                H8[(size_t)row * 128 + nt * 16 + lrow] = f32_to_fp8_b(dv[r] * acc[nt][r]);
        }
    }
}

// ---------------- Layer-1 aggregation FUSED with the W2 GEMM ----------------
// R13-proven agg structure (quarter-wave per node). R9: the block's 16 nodes
// are consecutive, so their CSR col entries are ONE contiguous range --
// stage it into LDS once (coalesced), then the gather loop reads indices via
// LDS broadcast instead of a serialized global round-trip per 8-edge batch.
// Quarter-uniform fallback to global col for pathological blocks (>COLCAP).
#define ACC8(u) \
    a0 += fp8_fv2<false>((u).x); a1 += fp8_fv2<true>((u).x); \
    a2 += fp8_fv2<false>((u).y); a3 += fp8_fv2<true>((u).y);

__global__ __launch_bounds__(256) void k_agg_relu_gemm(const unsigned* __restrict__ hs,
                                                       const float* __restrict__ dinv,
                                                       const int* __restrict__ row_ptr,
                                                       const int* __restrict__ col,
                                                       const float* __restrict__ bias,
                                                       const unsigned* __restrict__ Bp2,
                                                       unsigned short* __restrict__ H16,
                                                       int n) {
    __shared__ unsigned s_a[16][68];
    __shared__ int s_rp[17];
    __shared__ int s_col[COLCAP];
    int tid = threadIdx.x;
    int q16 = tid >> 4;                 // local node 0..15
    int node0 = blockIdx.x * 16;
    int node = node0 + q16;
    int l = tid & 15;
    bool alive = node < n;
    int nodeC = alive ? node : (n - 1);
    if (tid < 17) s_rp[tid] = row_ptr[min(node0 + tid, n)];
    __syncthreads();
    int base = s_rp[0];
    int total = s_rp[16] - base;
    int nld = min(total, COLCAP);
    for (int i = tid; i < nld; i += 256) s_col[i] = col[base + i];
    __syncthreads();

    const uint2* hrow = (const uint2*)hs;
    fv2 a0 = {0.f, 0.f}, a1 = {0.f, 0.f}, a2 = {0.f, 0.f}, a3 = {0.f, 0.f};
    if (alive) {   // self term
        uint2 u = hrow[(size_t)node * 16 + l];
        ACC8(u)
    }
    int kk = s_rp[q16] - base;
    int kend = s_rp[q16 + 1] - base;
    if (kend <= COLCAP) {   // fast path: indices from LDS (broadcast reads)
        for (; kk + 8 <= kend; kk += 8) {
            int cA = s_col[kk + 0], cB = s_col[kk + 1], cC = s_col[kk + 2], cD = s_col[kk + 3];
            int cE = s_col[kk + 4], cF = s_col[kk + 5], cG = s_col[kk + 6], cH = s_col[kk + 7];
            uint2 uA = hrow[(size_t)cA * 16 + l];
            uint2 uB = hrow[(size_t)cB * 16 + l];
            uint2 uC = hrow[(size_t)cC * 16 + l];
            uint2 uD = hrow[(size_t)cD * 16 + l];
            uint2 uE = hrow[(size_t)cE * 16 + l];
            uint2 uF = hrow[(size_t)cF * 16 + l];
            uint2 uG = hrow[(size_t)cG * 16 + l];
            uint2 uH = hrow[(size_t)cH * 16 + l];
            ACC8(uA) ACC8(uB) ACC8(uC) ACC8(uD)
            ACC8(uE) ACC8(uF) ACC8(uG) ACC8(uH)
        }
        for (; kk + 4 <= kend; kk += 4) {
            int cA = s_col[kk + 0], cB = s_col[kk + 1], cC = s_col[kk + 2], cD = s_col[kk + 3];
            uint2 uA = hrow[(size_t)cA * 16 + l];
            uint2 uB = hrow[(size_t)cB * 16 + l];
            uint2 uC = hrow[(size_t)cC * 16 + l];
            uint2 uD = hrow[(size_t)cD * 16 + l];
            ACC8(uA) ACC8(uB) ACC8(uC) ACC8(uD)
        }
        for (; kk < kend; ++kk) {
            uint2 u = hrow[(size_t)s_col[kk] * 16 + l];
            ACC8(u)
        }
    } else {                 // rare fallback: global col
        const int* cp = col + base;
        for (; kk + 4 <= kend; kk += 4) {
            int cA = cp[kk + 0], cB = cp[kk + 1], cC = cp[kk + 2], cD = cp[kk + 3];
            uint2 uA = hrow[(size_t)cA * 16 + l];
            uint2 uB = hrow[(size_t)cB * 16 + l];
            uint2 uC = hrow[(size_t)cC * 16 + l];
            uint2 uD = hrow[(size_t)cD * 16 + l];
            ACC8(uA) ACC8(uB) ACC8(uC) ACC8(uD)
        }
        for (; kk < kend; ++kk) {
            uint2 u = hrow[(size_t)cp[kk] * 16 + l];
            ACC8(u)
        }
    }
    // epilogue: every lane finalizes its own 8 columns -> bf16 into LDS tile
    {
        float di = dinv[nodeC];
        float4 b4a = *(const float4*)(bias + 8 * l);
        float4 b4b = *(const float4*)(bias + 8 * l + 4);
        float v0 = fmaf(di, a0.x, b4a.x);
        float v1 = fmaf(di, a0.y, b4a.y);
        float v2 = fmaf(di, a1.x, b4a.z);
        float v3 = fmaf(di, a1.y, b4a.w);
        float v4 = fmaf(di, a2.x, b4b.x);
        float v5 = fmaf(di, a2.y, b4b.y);
        float v6 = fmaf(di, a3.x, b4b.z);
        float v7 = fmaf(di, a3.y, b4b.w);
        v0 = v0 > 0.f ? v0 : 0.f;
        v1 = v1 > 0.f ? v1 : 0.f;
        v2 = v2 > 0.f ? v2 : 0.f;
        v3 = v3 > 0.f ? v3 : 0.f;
        v4 = v4 > 0.f ? v4 : 0.f;
        v5 = v5 > 0.f ? v5 : 0.f;
        v6 = v6 > 0.f ? v6 : 0.f;
        v7 = v7 > 0.f ? v7 : 0.f;
        uint4 o = {pack_bf16x2(v0, v1), pack_bf16x2(v2, v3),
                   pack_bf16x2(v4, v5), pack_bf16x2(v6, v7)};
        *(uint4*)&s_a[q16][4 * l] = o;
    }
    __syncthreads();
    // W2 GEMM: 16 nodes x 128 @ 128 x 64. Wave w owns N-tile nt=w (16 cols).
    // Fragment layouts identical to the standalone gemm64 (A: row=lane&15,
    // k-chunk=q*16+4*quad uints; C: row=quad*4+r, col=nt*16+(lane&15)).
    {
        int lane = threadIdx.x & 63;
        int w = threadIdx.x >> 6;
        int quad = lane >> 4;
        int lrow = lane & 15;
        f32x4 acc = (f32x4){0.f, 0.f, 0.f, 0.f};
        for (int q = 0; q < 4; ++q) {
            FragU a, b;
            a.u4 = *(const uint4*)&s_a[lrow][16 * q + 4 * quad];
            b.u4 = *(const uint4*)(Bp2 + ((size_t)(q * 4 + w) * 64 + lane) * 4);
            acc = __builtin_amdgcn_mfma_f32_16x16x32_bf16(a.s, b.s, acc, 0, 0, 0);
        }
        int rbase = blockIdx.x * 16 + quad * 4;
        for (int r = 0; r < 4; ++r) {
            int nd = rbase + r;
            if (nd < n)
                H16[(size_t)nd * 64 + w * 16 + lrow] = bf16_rne(dinv[nd] * acc[r]);
        }
    }
}

// Layer 2: hs rows = 16 uint2 (64 bf16). Lane owns bf16 cols 4l..4l+3.
// Same LDS col-index staging; fused log_softmax (16-lane quarter reduce).
#define ACCL(u) \
    aX += bfpair((u).x); aY += bfpair((u).y);

__global__ __launch_bounds__(256) void k_agg_lsm(const unsigned* __restrict__ hs,
                                                 const float* __restrict__ dinv,
                                                 const int* __restrict__ row_ptr,
                                                 const int* __restrict__ col,
                                                 const float* __restrict__ bias,
                                                 float* __restrict__ out, int n) {
    __shared__ int s_rp[17];
    __shared__ int s_col[COLCAP];
    int tid = threadIdx.x;
    int q16 = tid >> 4;
    int node0 = blockIdx.x * 16;
    int node = node0 + q16;
    int l = tid & 15;
    bool alive = node < n;
    int nodeC = alive ? node : (n - 1);
    if (tid < 17) s_rp[tid] = row_ptr[min(node0 + tid, n)];
    __syncthreads();
    int base = s_rp[0];
    int total = s_rp[16] - base;
    int nld = min(total, COLCAP);
    for (int i = tid; i < nld; i += 256) s_col[i] = col[base + i];
    __syncthreads();

    const uint2* hrow = (const uint2*)hs;
    fv2 aX = {0.f, 0.f}, aY = {0.f, 0.f};
    if (alive) {   // self term
        uint2 u = hrow[(size_t)node * 16 + l];
        ACCL(u)
    }
    int kk = s_rp[q16] - base;
    int kend = s_rp[q16 + 1] - base;
    if (kend <= COLCAP) {
        for (; kk + 8 <= kend; kk += 8) {
            int cA = s_col[kk + 0], cB = s_col[kk + 1], cC = s_col[kk + 2], cD = s_col[kk + 3];
            int cE = s_col[kk + 4], cF = s_col[kk + 5], cG = s_col[kk + 6], cH = s_col[kk + 7];
            uint2 uA = hrow[(size_t)cA * 16 + l];
            uint2 uB = hrow[(size_t)cB * 16 + l];
            uint2 uC = hrow[(size_t)cC * 16 + l];
            uint2 uD = hrow[(size_t)cD * 16 + l];
            uint2 uE = hrow[(size_t)cE * 16 + l];
            uint2 uF = hrow[(size_t)cF * 16 + l];
            uint2 uG = hrow[(size_t)cG * 16 + l];
            uint2 uH = hrow[(size_t)cH * 16 + l];
            ACCL(uA) ACCL(uB) ACCL(uC) ACCL(uD)
            ACCL(uE) ACCL(uF) ACCL(uG) ACCL(uH)
        }
        for (; kk + 4 <= kend; kk += 4) {
            int cA = s_col[kk + 0], cB = s_col[kk + 1], cC = s_col[kk + 2], cD = s_col[kk + 3];
            uint2 uA = hrow[(size_t)cA * 16 + l];
            uint2 uB = hrow[(size_t)cB * 16 + l];
            uint2 uC = hrow[(size_t)cC * 16 + l];
            uint2 uD = hrow[(size_t)cD * 16 + l];
            ACCL(uA) ACCL(uB) ACCL(uC) ACCL(uD)
        }
        for (; kk < kend; ++kk) {
            uint2 u = hrow[(size_t)s_col[kk] * 16 + l];
            ACCL(u)
        }
    } else {
        const int* cp = col + base;
        for (; kk + 4 <= kend; kk += 4) {
            int cA = cp[kk + 0], cB = cp[kk + 1], cC = cp[kk + 2], cD = cp[kk + 3];
            uint2 uA = hrow[(size_t)cA * 16 + l];
            uint2 uB = hrow[(size_t)cB * 16 + l];
            uint2 uC = hrow[(size_t)cC * 16 + l];
            uint2 uD = hrow[(size_t)cD * 16 + l];
            ACCL(uA) ACCL(uB) ACCL(uC) ACCL(uD)
        }
        for (; kk < kend; ++kk) {
            uint2 u = hrow[(size_t)cp[kk] * 16 + l];
            ACCL(u)
        }
    }
    float di = dinv[nodeC];
    float4 b4 = *(const float4*)(bias + 4 * l);
    float v0 = fmaf(di, aX.x, b4.x);
    float v1 = fmaf(di, aX.y, b4.y);
    float v2 = fmaf(di, aY.x, b4.z);
    float v3 = fmaf(di, aY.y, b4.w);
    float m = fmaxf(fmaxf(v0, v1), fmaxf(v2, v3));
    for (int off = 8; off; off >>= 1) m = fmaxf(m, __shfl_xor(m, off));
    float s = __expf(v0 - m) + __expf(v1 - m) + __expf(v2 - m) + __expf(v3 - m);
    for (int off = 8; off; off >>= 1) s += __shfl_xor(s, off);
    float ls = __logf(s);
    if (alive) {
        float4 o = {v0 - m - ls, v1 - m - ls, v2 - m - ls, v3 - m - ls};
        *(float4*)(out + (size_t)node * 64 + 4 * l) = o;
    }
}

// ---------------- launcher ----------------

extern "C" void kernel_launch(void* const* d_in, const int* in_sizes, int n_in,
                              void* d_out, int out_size, void* d_ws, size_t ws_size,
                              hipStream_t stream) {
    const float* x  = (const float*)d_in[0];
    const int*   ei = (const int*)d_in[1];
    const float* W1 = (const float*)d_in[2];
    const float* b1 = (const float*)d_in[3];
    const float* W2 = (const float*)d_in[4];
    const float* b2 = (const float*)d_in[5];
    float* out = (float*)d_out;

    const int N = in_sizes[0] / 128;   // 100000
    const int E = in_sizes[1] / 2;     // 1600000
    const int* src = ei;
    const int* dst = ei + E;
    const int npp = (N + NPART - 1) / NPART;           // 12500
    const int capE = (E + NPART - 1) / NPART + 32768;  // segment capacity + slack
    int srcb = 1;
    while ((1 << srcb) < N) ++srcb;                    // 17 for N=100000

    char* w = (char*)d_ws;
    size_t off = 0;
    auto alloc = [&](size_t bytes) -> void* {
        void* p = w + off;
        off += (bytes + 255) & ~(size_t)255;
        return p;
    };
    int*      row_ptr  = (int*)alloc((size_t)(N + 1) * 4);
    int*      colarr   = (int*)alloc((size_t)E * 4);
    int*      partials = (int*)alloc(256 * 4);
    int*      cursor8  = (int*)alloc(8 * 4);
    float*    dinv     = (float*)alloc((size_t)N * 4);
    unsigned* h1f8     = (unsigned*)alloc((size_t)N * 32 * 4);  // fp8 X@W1 scaled (12.8MB)
    unsigned* h2b      = (unsigned*)alloc((size_t)N * 32 * 4);  // bf16 a1@W2 scaled (12.8MB)
    unsigned* Bp1      = (unsigned*)alloc(4 * 8 * 64 * 16);     // W1 frag stream 32KB
    unsigned* Bp2      = (unsigned*)alloc(4 * 4 * 64 * 16);     // W2 frag stream 16KB
    // pairs (7.5 MB) + cntarr (12.8 MB) alias h1f8+h2b (25.6 MB contiguous);
    // both are dead before k_gemm128_mfma writes h1f8.
    unsigned* pairsU   = (unsigned*)h1f8;
    int*      cntarr   = (int*)((char*)h1f8 + (size_t)NPART * capE * 4);
    (void)ws_size; (void)n_in; (void)out_size;

    int nscan = (N + 1023) / 1024;
    int nbb = (E + EB - 1) / EB;       // 782 bucket blocks
    int ngemm = (N + 63) / 64;

    k_packW2<<<2, 256, 0, stream>>>(W1, Bp1, W2, Bp2, cursor8, partials);
    k_bucket_ballot<<<nbb, 256, 0, stream>>>(src, dst, cursor8, pairsU,
                                             E, npp, capE, srcb);
    k_count_part<<<NPART * KB, 256, 0, stream>>>(pairsU, cursor8, cntarr,
                                                 npp, capE, srcb);
    k_indeg_scan<<<nscan, 256, 0, stream>>>(cntarr, dinv, row_ptr, partials, N, npp);
    k_finalize_bases<<<(N + 255) / 256, 256, 0, stream>>>(row_ptr, partials, cntarr,
                                                          N, E, npp);
    k_fill2<<<NPART * KB, 256, 0, stream>>>(pairsU, cursor8, cntarr, colarr,
                                            npp, capE, srcb);

    k_gemm128_mfma<<<ngemm, 256, 0, stream>>>(x, Bp1, dinv, (unsigned char*)h1f8, N);
    k_agg_relu_gemm<<<(N + 15) / 16, 256, 0, stream>>>(h1f8, dinv, row_ptr, colarr,
                                                       b1, Bp2, (unsigned short*)h2b, N);
    k_agg_lsm<<<(N + 15) / 16, 256, 0, stream>>>(h2b, dinv, row_ptr, colarr, b2, out, N);
}